// Round 1
// baseline (424.630 us; speedup 1.0000x reference)
//
#include <hip/hip_runtime.h>
#include <math.h>

#define E_NUM 2048
#define A_N   8
#define ROWS  (E_NUM*A_N)   // 16384
#define NACTD 16
#define RDIM  64
#define OBSD  128
#define ATTND 64
#define HIDD  256
#define INPD  152

// ---- ws layout (float offsets) ----
#define T_FC1 0          // 152*64 = 9728
#define T_WIH 9728       // 64*192 = 12288
#define T_WHH 22016      // 64*192 = 12288
#define T_TM1 34304      // 72*256 = 18432
#define T_TM2 52736      // 256*16 = 4096
#define T_WM1 56832      // 256*256 = 65536
#define T_WM2 122368     // 256*128 = 32768
#define T_WQ  155136     // 256*64 = 16384
#define T_WK  171520     // 16*64  = 1024
#define T_WV1 172544     // 80*64  = 5120
#define T_WV2 177664     // 64*16  = 1024
#define O_ACT 178688     // 16384*16  = 262144  (act_off[e*8+j][16])
#define O_ONH 440832     // 16384*128 = 2097152 (o_next_hat)
#define O_QRY 2537984    // 16384*64  = 1048576
#define O_KEY 3586560    // 16384*64  = 1048576 (key_off)
#define O_VAL 4635136    // 16384*16  = 262144  (value_off)
#define O_L1P 4897280    // 64
#define O_L2P 4897344    // 1024
// total = 4898368 floats = ~18.7 MB

// d_out: q_reflect [0,262144) ; h [262144,1310720) ; loss1 @1310720 ; loss2 @1310721
#define DO_H   262144
#define DO_L1  1310720
#define DO_L2  1310721

struct TPtrs {
  const float* src[11];
  int O[11];
  int K[11];
  int dstOff[11];
};

// one block per matrix: WT[k*O+o] = W[o*K+k]
__global__ __launch_bounds__(256) void k_transpose(TPtrs p, float* __restrict__ ws) {
  int b = blockIdx.x;
  const float* s = p.src[b];
  float* d = ws + p.dstOff[b];
  int O = p.O[b], K = p.K[b], n = O * K;
  for (int i = threadIdx.x; i < n; i += 256) {
    int o = i / K, k = i - o * K;
    d[k * O + o] = s[i];
  }
}

// fused fc1 + GRU: wave per row
__global__ __launch_bounds__(256) void k_trunk(
    const float* __restrict__ inp, const float* __restrict__ hin,
    const float* __restrict__ ws, const float* __restrict__ fc1b,
    const float* __restrict__ bih, const float* __restrict__ bhh,
    float* __restrict__ hout)
{
  __shared__ float in_s[4][INPD];
  __shared__ float x_s[4][64];
  __shared__ float h_s[4][64];
  int w = threadIdx.x >> 6, lane = threadIdx.x & 63;
  int row = blockIdx.x * 4 + w;
  const float* fc1T = ws + T_FC1;
  const float* wihT = ws + T_WIH;
  const float* whhT = ws + T_WHH;
  for (int k = lane; k < INPD; k += 64) in_s[w][k] = inp[(size_t)row * INPD + k];
  h_s[w][lane] = hin[(size_t)row * 64 + lane];
  __syncthreads();
  float acc = fc1b[lane];
  for (int k = 0; k < INPD; k++) acc = fmaf(in_s[w][k], fc1T[k * 64 + lane], acc);
  x_s[w][lane] = fmaxf(acc, 0.f);
  __syncthreads();
  float ir = bih[lane], iz = bih[64 + lane], inn = bih[128 + lane];
  float hr = bhh[lane], hz = bhh[64 + lane], hn = bhh[128 + lane];
  for (int k = 0; k < 64; k++) {
    float xv = x_s[w][k], hv = h_s[w][k];
    ir  = fmaf(xv, wihT[k * 192 + lane],        ir);
    iz  = fmaf(xv, wihT[k * 192 + 64  + lane],  iz);
    inn = fmaf(xv, wihT[k * 192 + 128 + lane],  inn);
    hr  = fmaf(hv, whhT[k * 192 + lane],        hr);
    hz  = fmaf(hv, whhT[k * 192 + 64  + lane],  hz);
    hn  = fmaf(hv, whhT[k * 192 + 128 + lane],  hn);
  }
  float r = 1.f / (1.f + expf(-(ir + hr)));
  float z = 1.f / (1.f + expf(-(iz + hz)));
  float n = tanhf(fmaf(r, hn, inn));
  float h0 = h_s[w][lane];
  hout[(size_t)row * 64 + lane] = (1.f - z) * n + z * h0;
}

// teammate MLP over (e,j) rows: [h(64), onehot_j(8)] -> 256 relu -> 16
__global__ __launch_bounds__(256) void k_tm(
    const float* __restrict__ h, const float* __restrict__ ws,
    const float* __restrict__ b1, const float* __restrict__ b2,
    float* __restrict__ act)
{
  __shared__ float in_s[4][72];
  __shared__ float hid_s[4][256];
  int w = threadIdx.x >> 6, lane = threadIdx.x & 63;
  int row = blockIdx.x * 4 + w;
  int j = row & 7;
  const float* w1T = ws + T_TM1;
  const float* w2T = ws + T_TM2;
  in_s[w][lane] = h[(size_t)row * 64 + lane];
  if (lane < 8) in_s[w][64 + lane] = (lane == j) ? 1.f : 0.f;
  __syncthreads();
  float a0 = b1[lane], a1 = b1[64 + lane], a2 = b1[128 + lane], a3 = b1[192 + lane];
  for (int k = 0; k < 72; k++) {
    float v = in_s[w][k];
    a0 = fmaf(v, w1T[k * 256 + lane],        a0);
    a1 = fmaf(v, w1T[k * 256 + 64  + lane],  a1);
    a2 = fmaf(v, w1T[k * 256 + 128 + lane],  a2);
    a3 = fmaf(v, w1T[k * 256 + 192 + lane],  a3);
  }
  hid_s[w][lane]        = fmaxf(a0, 0.f);
  hid_s[w][64  + lane]  = fmaxf(a1, 0.f);
  hid_s[w][128 + lane]  = fmaxf(a2, 0.f);
  hid_s[w][192 + lane]  = fmaxf(a3, 0.f);
  __syncthreads();
  int o = lane & 15, seg = lane >> 4;
  float s = 0.f;
  for (int kk = 0; kk < 64; kk++) {
    int k = seg * 64 + kk;
    s = fmaf(hid_s[w][k], w2T[k * 16 + o], s);
  }
  s += __shfl_xor(s, 16);
  s += __shfl_xor(s, 32);
  if (lane < 16) act[(size_t)row * 16 + lane] = s + b2[lane];
}

// CE over off-diag teammate rows (weight 7 applied at final reduce)
__global__ __launch_bounds__(256) void k_ce(
    const float* __restrict__ act, const int* __restrict__ u, float* __restrict__ l1p)
{
  int tid = blockIdx.x * 256 + threadIdx.x;
  const float* a = act + (size_t)tid * 16;
  float m = a[0];
  for (int c = 1; c < 16; c++) m = fmaxf(m, a[c]);
  float sum = 0.f;
  for (int c = 0; c < 16; c++) sum += expf(a[c] - m);
  int lbl = u[tid];
  float ce = -(a[lbl] - m - logf(sum));
  __shared__ float red[256];
  red[threadIdx.x] = ce;
  __syncthreads();
  for (int s = 128; s > 0; s >>= 1) {
    if (threadIdx.x < s) red[threadIdx.x] += red[threadIdx.x + s];
    __syncthreads();
  }
  if (threadIdx.x == 0) l1p[blockIdx.x] = red[0];
}

// world model: [obs(128), am(128)] -> 256 relu -> 128
__global__ __launch_bounds__(256) void k_wm(
    const float* __restrict__ obs, const float* __restrict__ act,
    const float* __restrict__ ws, const float* __restrict__ b1,
    const float* __restrict__ b2, float* __restrict__ onh)
{
  __shared__ float in_s[4][256];
  __shared__ float hid_s[4][256];
  int w = threadIdx.x >> 6, lane = threadIdx.x & 63;
  int row = blockIdx.x * 4 + w;
  int i = row & 7, e = row >> 3;
  const float* w1T = ws + T_WM1;
  const float* w2T = ws + T_WM2;
  for (int t = 0; t < 4; t++) {
    int k = t * 64 + lane;
    float v;
    if (k < 128) v = obs[(size_t)row * 128 + k];
    else {
      int jj = (k - 128) >> 4;
      v = (jj == i) ? 0.f : act[(size_t)e * 128 + (k - 128)];
    }
    in_s[w][k] = v;
  }
  __syncthreads();
  float a0 = b1[lane], a1 = b1[64 + lane], a2 = b1[128 + lane], a3 = b1[192 + lane];
  for (int k = 0; k < 256; k++) {
    float v = in_s[w][k];
    a0 = fmaf(v, w1T[k * 256 + lane],        a0);
    a1 = fmaf(v, w1T[k * 256 + 64  + lane],  a1);
    a2 = fmaf(v, w1T[k * 256 + 128 + lane],  a2);
    a3 = fmaf(v, w1T[k * 256 + 192 + lane],  a3);
  }
  hid_s[w][lane]        = fmaxf(a0, 0.f);
  hid_s[w][64  + lane]  = fmaxf(a1, 0.f);
  hid_s[w][128 + lane]  = fmaxf(a2, 0.f);
  hid_s[w][192 + lane]  = fmaxf(a3, 0.f);
  __syncthreads();
  float c0 = b2[lane], c1 = b2[64 + lane];
  for (int k = 0; k < 256; k++) {
    float v = hid_s[w][k];
    c0 = fmaf(v, w2T[k * 128 + lane],       c0);
    c1 = fmaf(v, w2T[k * 128 + 64 + lane],  c1);
  }
  onh[(size_t)row * 128 + lane]      = c0;
  onh[(size_t)row * 128 + 64 + lane] = c1;
}

__global__ __launch_bounds__(256) void k_mse(
    const float* __restrict__ onh, const float* __restrict__ obsn, float* __restrict__ l2p)
{
  size_t tid = blockIdx.x * 256 + threadIdx.x;
  float s = 0.f;
  for (size_t idx = tid; idx < (size_t)ROWS * 128; idx += (size_t)1024 * 256) {
    float d = onh[idx] - obsn[idx];
    s = fmaf(d, d, s);
  }
  __shared__ float red[256];
  red[threadIdx.x] = s;
  __syncthreads();
  for (int st = 128; st > 0; st >>= 1) {
    if (threadIdx.x < st) red[threadIdx.x] += red[threadIdx.x + st];
    __syncthreads();
  }
  if (threadIdx.x == 0) l2p[blockIdx.x] = red[0];
}

// query = [obs, o_next_hat] @ wqT + b
__global__ __launch_bounds__(256) void k_query(
    const float* __restrict__ obs, const float* __restrict__ onh,
    const float* __restrict__ ws, const float* __restrict__ bq, float* __restrict__ qry)
{
  __shared__ float in_s[4][256];
  int w = threadIdx.x >> 6, lane = threadIdx.x & 63;
  int row = blockIdx.x * 4 + w;
  for (int t = 0; t < 4; t++) {
    int k = t * 64 + lane;
    in_s[w][k] = (k < 128) ? obs[(size_t)row * 128 + k] : onh[(size_t)row * 128 + (k - 128)];
  }
  __syncthreads();
  const float* wqT = ws + T_WQ;
  float acc = bq[lane];
  for (int k = 0; k < 256; k++) acc = fmaf(in_s[w][k], wqT[k * 64 + lane], acc);
  qry[(size_t)row * 64 + lane] = acc;
}

// key_off = act_off @ wkT + b   (K=16)
__global__ __launch_bounds__(256) void k_key(
    const float* __restrict__ act, const float* __restrict__ ws,
    const float* __restrict__ bk, float* __restrict__ key)
{
  int w = threadIdx.x >> 6, lane = threadIdx.x & 63;
  int row = blockIdx.x * 4 + w;
  const float* wkT = ws + T_WK;
  float acc = bk[lane];
  for (int k = 0; k < 16; k++) acc = fmaf(act[(size_t)row * 16 + k], wkT[k * 64 + lane], acc);
  key[(size_t)row * 64 + lane] = acc;
}

// value_off: [h(64), act_off(16)] -> 64 relu -> 16
__global__ __launch_bounds__(256) void k_value(
    const float* __restrict__ h, const float* __restrict__ act,
    const float* __restrict__ ws, const float* __restrict__ b1,
    const float* __restrict__ b2, float* __restrict__ val)
{
  __shared__ float in_s[4][80];
  __shared__ float hid_s[4][64];
  int w = threadIdx.x >> 6, lane = threadIdx.x & 63;
  int row = blockIdx.x * 4 + w;
  in_s[w][lane] = h[(size_t)row * 64 + lane];
  if (lane < 16) in_s[w][64 + lane] = act[(size_t)row * 16 + lane];
  __syncthreads();
  const float* w1T = ws + T_WV1;
  const float* w2T = ws + T_WV2;
  float acc = b1[lane];
  for (int k = 0; k < 80; k++) acc = fmaf(in_s[w][k], w1T[k * 64 + lane], acc);
  hid_s[w][lane] = fmaxf(acc, 0.f);
  __syncthreads();
  int o = lane & 15, seg = lane >> 4;
  float s = 0.f;
  for (int kk = 0; kk < 16; kk++) {
    int k = seg * 16 + kk;
    s = fmaf(hid_s[w][k], w2T[k * 16 + o], s);
  }
  s += __shfl_xor(s, 16);
  s += __shfl_xor(s, 32);
  if (lane < 16) val[(size_t)row * 16 + lane] = s + b2[lane];
}

// attention + output: wave per row b=(e,i)
__global__ __launch_bounds__(256) void k_attn(
    const float* __restrict__ qry, const float* __restrict__ key,
    const float* __restrict__ val, float* __restrict__ qout)
{
  __shared__ float q_s[4][64];
  int w = threadIdx.x >> 6, lane = threadIdx.x & 63;
  int b = blockIdx.x * 4 + w;
  int i = b & 7, e = b >> 3;
  q_s[w][lane] = qry[(size_t)b * 64 + lane];
  __syncthreads();
  int j = lane >> 3, p = lane & 7;
  const float* krow = key + ((size_t)e * 8 + j) * 64;
  float acc = 0.f;
  for (int t = 0; t < 8; t++) {
    int d = p * 8 + t;
    acc = fmaf(q_s[w][d], krow[d], acc);
  }
  acc += __shfl_xor(acc, 1);
  acc += __shfl_xor(acc, 2);
  acc += __shfl_xor(acc, 4);
  float score = (j == i) ? -1e9f : acc * 0.125f;   // /sqrt(64)
  float sc[8];
  float m = -1e30f;
  for (int jj = 0; jj < 8; jj++) {
    sc[jj] = __shfl(score, jj * 8);
    m = fmaxf(m, sc[jj]);
  }
  float ssum = 0.f;
  for (int jj = 0; jj < 8; jj++) { sc[jj] = expf(sc[jj] - m); ssum += sc[jj]; }
  float inv = 1.f / ssum;
  int c = lane & 15, g = lane >> 4;
  const float* vbase = val + (size_t)e * 128;
  float outv = sc[g] * inv * vbase[g * 16 + c] + sc[g + 4] * inv * vbase[(g + 4) * 16 + c];
  outv += __shfl_xor(outv, 16);
  outv += __shfl_xor(outv, 32);
  if (lane < 16) qout[(size_t)b * 16 + lane] = outv;
}

__global__ __launch_bounds__(256) void k_losses(
    const float* __restrict__ l1p, const float* __restrict__ l2p, float* __restrict__ dout)
{
  __shared__ float red[256];
  int tid = threadIdx.x;
  float s1 = (tid < 64) ? l1p[tid] : 0.f;
  float s2 = 0.f;
  for (int i = tid; i < 1024; i += 256) s2 += l2p[i];
  red[tid] = s1;
  __syncthreads();
  for (int s = 128; s > 0; s >>= 1) {
    if (tid < s) red[tid] += red[tid + s];
    __syncthreads();
  }
  float S1 = red[0];
  __syncthreads();
  red[tid] = s2;
  __syncthreads();
  for (int s = 128; s > 0; s >>= 1) {
    if (tid < s) red[tid] += red[tid + s];
    __syncthreads();
  }
  if (tid == 0) {
    dout[DO_L1] = S1 * 7.f / 131072.f;      // TW = 1
    dout[DO_L2] = red[0] / 2097152.f;       // WW = 1
  }
}

extern "C" void kernel_launch(void* const* d_in, const int* in_sizes, int n_in,
                              void* d_out, int out_size, void* d_ws, size_t ws_size,
                              hipStream_t stream) {
  const float* inputs   = (const float*)d_in[0];
  const float* hidden   = (const float*)d_in[1];
  const float* obs      = (const float*)d_in[2];
  const float* obs_next = (const float*)d_in[3];
  const int*   u        = (const int*)d_in[4];
  const float* fc1_w = (const float*)d_in[5];   const float* fc1_b = (const float*)d_in[6];
  const float* wih   = (const float*)d_in[7];   const float* bih   = (const float*)d_in[8];
  const float* whh   = (const float*)d_in[9];   const float* bhh   = (const float*)d_in[10];
  const float* tm_w1 = (const float*)d_in[11];  const float* tm_b1 = (const float*)d_in[12];
  const float* tm_w2 = (const float*)d_in[13];  const float* tm_b2 = (const float*)d_in[14];
  const float* wm_w1 = (const float*)d_in[15];  const float* wm_b1 = (const float*)d_in[16];
  const float* wm_w2 = (const float*)d_in[17];  const float* wm_b2 = (const float*)d_in[18];
  const float* wq_w  = (const float*)d_in[19];  const float* wq_b  = (const float*)d_in[20];
  const float* wk_w  = (const float*)d_in[21];  const float* wk_b  = (const float*)d_in[22];
  const float* wv1_w = (const float*)d_in[23];  const float* wv1_b = (const float*)d_in[24];
  const float* wv2_w = (const float*)d_in[25];  const float* wv2_b = (const float*)d_in[26];

  float* ws   = (float*)d_ws;
  float* out  = (float*)d_out;
  float* hbuf = out + DO_H;

  TPtrs tp;
  const float* srcs[11] = {fc1_w, wih, whh, tm_w1, tm_w2, wm_w1, wm_w2, wq_w, wk_w, wv1_w, wv2_w};
  int Os[11]  = {64, 192, 192, 256, 16, 256, 128, 64, 64, 64, 16};
  int Ks[11]  = {152, 64, 64, 72, 256, 256, 256, 256, 16, 80, 64};
  int Ofs[11] = {T_FC1, T_WIH, T_WHH, T_TM1, T_TM2, T_WM1, T_WM2, T_WQ, T_WK, T_WV1, T_WV2};
  for (int i = 0; i < 11; i++) { tp.src[i] = srcs[i]; tp.O[i] = Os[i]; tp.K[i] = Ks[i]; tp.dstOff[i] = Ofs[i]; }

  dim3 blk(256);
  k_transpose<<<11, blk, 0, stream>>>(tp, ws);
  k_trunk<<<ROWS / 4, blk, 0, stream>>>(inputs, hidden, ws, fc1_b, bih, bhh, hbuf);
  k_tm<<<ROWS / 4, blk, 0, stream>>>(hbuf, ws, tm_b1, tm_b2, ws + O_ACT);
  k_ce<<<ROWS / 256, blk, 0, stream>>>(ws + O_ACT, u, ws + O_L1P);
  k_wm<<<ROWS / 4, blk, 0, stream>>>(obs, ws + O_ACT, ws, wm_b1, wm_b2, ws + O_ONH);
  k_mse<<<1024, blk, 0, stream>>>(ws + O_ONH, obs_next, ws + O_L2P);
  k_query<<<ROWS / 4, blk, 0, stream>>>(obs, ws + O_ONH, ws, wq_b, ws + O_QRY);
  k_key<<<ROWS / 4, blk, 0, stream>>>(ws + O_ACT, ws, wk_b, ws + O_KEY);
  k_value<<<ROWS / 4, blk, 0, stream>>>(hbuf, ws + O_ACT, ws, wv1_b, wv2_b, ws + O_VAL);
  k_attn<<<ROWS / 4, blk, 0, stream>>>(ws + O_QRY, ws + O_KEY, ws + O_VAL, out);
  k_losses<<<1, blk, 0, stream>>>(ws + O_L1P, ws + O_L2P, out);
}

// Round 2
// 171.534 us; speedup vs baseline: 2.4755x; 2.4755x over previous
//
#include <hip/hip_runtime.h>
#include <math.h>

#define E_NUM 2048
#define A_N   8
#define ROWS  (E_NUM*A_N)   // 16384
#define INPD  152

// ---- ws layout (float offsets) ----
#define T_FC1 0          // 152*64 = 9728
#define T_WIH 9728       // 64*192 = 12288
#define T_WHH 22016      // 64*192 = 12288
#define T_TM1 34304      // 72*256 = 18432
#define T_TM2 52736      // 256*16 = 4096
#define T_WM1 56832      // 256*256 = 65536
#define T_WM2 122368     // 256*128 = 32768
#define T_WQ  155136     // 256*64 = 16384
#define T_WK  171520     // 16*64  = 1024
#define T_WV1 172544     // 80*64  = 5120
#define T_WV2 177664     // 64*16  = 1024
#define O_ACT 178688     // 16384*16  (act_off[e*8+j][16])
#define O_ONH 440832     // 16384*128 (o_next_hat)
#define O_QRY 2537984    // 16384*64
#define O_KEY 3586560    // 16384*64  (key_off)
#define O_VAL 4635136    // 16384*16  (value_off)
#define O_L1P 4897280    // 64
#define O_L2P 4897344    // 1024

// d_out: q_reflect [0,262144) ; h ; loss1 ; loss2
#define DO_H   262144
#define DO_L1  1310720
#define DO_L2  1310721

#define LD4(p) (*(const float4*)(p))

struct TPtrs {
  const float* src[11];
  int O[11];
  int K[11];
  int dstOff[11];
};

// 8 blocks per matrix: WT[k*O+o] = W[o*K+k]
__global__ __launch_bounds__(256) void k_transpose(TPtrs p, float* __restrict__ ws) {
  int b = blockIdx.x >> 3, sl = blockIdx.x & 7;
  const float* s = p.src[b];
  float* d = ws + p.dstOff[b];
  int O = p.O[b], K = p.K[b], n = O * K;
  for (int i = sl * 256 + threadIdx.x; i < n; i += 2048) {
    int o = i / K, k = i - o * K;
    d[k * O + o] = s[i];
  }
}

// fused fc1 + GRU: 32 rows/block, 8 rows/wave, col = lane
__global__ __launch_bounds__(256) void k_trunk(
    const float* __restrict__ inp, const float* __restrict__ hin,
    const float* __restrict__ ws, const float* __restrict__ fc1b,
    const float* __restrict__ bih, const float* __restrict__ bhh,
    float* __restrict__ hout)
{
  __shared__ __align__(16) float in_s[32 * INPD];
  __shared__ __align__(16) float x_s[32 * 64];
  __shared__ __align__(16) float h_s[32 * 64];
  int tid = threadIdx.x, w = tid >> 6, lane = tid & 63;
  int row0 = blockIdx.x * 32;
  for (int i = tid; i < 32 * INPD; i += 256) in_s[i] = inp[(size_t)row0 * INPD + i];
  for (int i = tid; i < 32 * 64;   i += 256) h_s[i]  = hin[(size_t)row0 * 64 + i];
  __syncthreads();
  const float* fc1T = ws + T_FC1;
  const float* wihT = ws + T_WIH;
  const float* whhT = ws + T_WHH;
  // fc1
  float acc[8];
#pragma unroll
  for (int r = 0; r < 8; r++) acc[r] = fc1b[lane];
  for (int k = 0; k < INPD; k += 4) {
    float b0 = fc1T[k * 64 + lane], b1 = fc1T[(k + 1) * 64 + lane];
    float b2 = fc1T[(k + 2) * 64 + lane], b3 = fc1T[(k + 3) * 64 + lane];
#pragma unroll
    for (int r = 0; r < 8; r++) {
      float4 a = LD4(in_s + (w * 8 + r) * INPD + k);
      acc[r] = fmaf(a.x, b0, fmaf(a.y, b1, fmaf(a.z, b2, fmaf(a.w, b3, acc[r]))));
    }
  }
#pragma unroll
  for (int r = 0; r < 8; r++) x_s[(w * 8 + r) * 64 + lane] = fmaxf(acc[r], 0.f);
  __syncthreads();
  // GRU: gate sums sr=i_r+h_r, sz=i_z+h_z ; si=i_n, sh=h_n
  float sr[8], sz[8], si[8], sh[8];
  float br = bih[lane] + bhh[lane], bz = bih[64 + lane] + bhh[64 + lane];
  float bin = bih[128 + lane], bhn = bhh[128 + lane];
#pragma unroll
  for (int r = 0; r < 8; r++) { sr[r] = br; sz[r] = bz; si[r] = bin; sh[r] = bhn; }
  for (int k = 0; k < 64; k += 4) {
    float bi0[4], bi1[4], bi2[4], bh0[4], bh1[4], bh2[4];
#pragma unroll
    for (int j = 0; j < 4; j++) {
      bi0[j] = wihT[(k + j) * 192 + lane];
      bi1[j] = wihT[(k + j) * 192 + 64 + lane];
      bi2[j] = wihT[(k + j) * 192 + 128 + lane];
      bh0[j] = whhT[(k + j) * 192 + lane];
      bh1[j] = whhT[(k + j) * 192 + 64 + lane];
      bh2[j] = whhT[(k + j) * 192 + 128 + lane];
    }
#pragma unroll
    for (int r = 0; r < 8; r++) {
      float4 xv = LD4(x_s + (w * 8 + r) * 64 + k);
      float4 hv = LD4(h_s + (w * 8 + r) * 64 + k);
      sr[r] = fmaf(xv.x, bi0[0], fmaf(xv.y, bi0[1], fmaf(xv.z, bi0[2], fmaf(xv.w, bi0[3], sr[r]))));
      sr[r] = fmaf(hv.x, bh0[0], fmaf(hv.y, bh0[1], fmaf(hv.z, bh0[2], fmaf(hv.w, bh0[3], sr[r]))));
      sz[r] = fmaf(xv.x, bi1[0], fmaf(xv.y, bi1[1], fmaf(xv.z, bi1[2], fmaf(xv.w, bi1[3], sz[r]))));
      sz[r] = fmaf(hv.x, bh1[0], fmaf(hv.y, bh1[1], fmaf(hv.z, bh1[2], fmaf(hv.w, bh1[3], sz[r]))));
      si[r] = fmaf(xv.x, bi2[0], fmaf(xv.y, bi2[1], fmaf(xv.z, bi2[2], fmaf(xv.w, bi2[3], si[r]))));
      sh[r] = fmaf(hv.x, bh2[0], fmaf(hv.y, bh2[1], fmaf(hv.z, bh2[2], fmaf(hv.w, bh2[3], sh[r]))));
    }
  }
#pragma unroll
  for (int r = 0; r < 8; r++) {
    float rg = 1.f / (1.f + expf(-sr[r]));
    float zg = 1.f / (1.f + expf(-sz[r]));
    float ng = tanhf(fmaf(rg, sh[r], si[r]));
    float h0 = h_s[(w * 8 + r) * 64 + lane];
    hout[(size_t)(row0 + w * 8 + r) * 64 + lane] = (1.f - zg) * ng + zg * h0;
  }
}

// teammate MLP over (e,j): [h(64), onehot_j(8)] -> 256 relu -> 16
__global__ __launch_bounds__(256) void k_tm(
    const float* __restrict__ h, const float* __restrict__ ws,
    const float* __restrict__ b1, const float* __restrict__ b2,
    float* __restrict__ act)
{
  __shared__ __align__(16) float h_s[32 * 64];
  __shared__ __align__(16) float hid_s[32 * 256];
  int tid = threadIdx.x, w = tid >> 6, lane = tid & 63;
  int row0 = blockIdx.x * 32;
  for (int i = tid; i < 32 * 64; i += 256) h_s[i] = h[(size_t)row0 * 64 + i];
  __syncthreads();
  const float* w1T = ws + T_TM1;
  const float* w2T = ws + T_TM2;
  float acc[8][4];
#pragma unroll
  for (int r = 0; r < 8; r++)
#pragma unroll
    for (int q = 0; q < 4; q++) acc[r][q] = b1[q * 64 + lane];
  for (int k = 0; k < 64; k += 4) {
    float b[4][4];
#pragma unroll
    for (int j = 0; j < 4; j++)
#pragma unroll
      for (int q = 0; q < 4; q++) b[j][q] = w1T[(k + j) * 256 + q * 64 + lane];
#pragma unroll
    for (int r = 0; r < 8; r++) {
      float4 a = LD4(h_s + (w * 8 + r) * 64 + k);
#pragma unroll
      for (int q = 0; q < 4; q++)
        acc[r][q] = fmaf(a.x, b[0][q], fmaf(a.y, b[1][q], fmaf(a.z, b[2][q], fmaf(a.w, b[3][q], acc[r][q]))));
    }
  }
  // onehot column: j = row&7 = r  (rows per wave are aligned to 8)
#pragma unroll
  for (int r = 0; r < 8; r++)
#pragma unroll
    for (int q = 0; q < 4; q++) {
      acc[r][q] += w1T[(64 + r) * 256 + q * 64 + lane];
      hid_s[(w * 8 + r) * 256 + q * 64 + lane] = fmaxf(acc[r][q], 0.f);
    }
  __syncthreads();
  int col = lane & 15, kq = lane >> 4;
  float a2[8] = {0, 0, 0, 0, 0, 0, 0, 0};
  for (int kk = 0; kk < 64; kk += 4) {
    int k = kq * 64 + kk;
    float b[4];
#pragma unroll
    for (int j = 0; j < 4; j++) b[j] = w2T[(k + j) * 16 + col];
#pragma unroll
    for (int r = 0; r < 8; r++) {
      float4 a = LD4(hid_s + (w * 8 + r) * 256 + k);
      a2[r] = fmaf(a.x, b[0], fmaf(a.y, b[1], fmaf(a.z, b[2], fmaf(a.w, b[3], a2[r]))));
    }
  }
#pragma unroll
  for (int r = 0; r < 8; r++) {
    a2[r] += __shfl_xor(a2[r], 16);
    a2[r] += __shfl_xor(a2[r], 32);
  }
  if (lane < 16)
#pragma unroll
    for (int r = 0; r < 8; r++)
      act[(size_t)(row0 + w * 8 + r) * 16 + col] = a2[r] + b2[col];
}

__global__ __launch_bounds__(256) void k_ce(
    const float* __restrict__ act, const int* __restrict__ u, float* __restrict__ l1p)
{
  int tid = blockIdx.x * 256 + threadIdx.x;
  const float* a = act + (size_t)tid * 16;
  float m = a[0];
  for (int c = 1; c < 16; c++) m = fmaxf(m, a[c]);
  float sum = 0.f;
  for (int c = 0; c < 16; c++) sum += expf(a[c] - m);
  int lbl = u[tid];
  float ce = -(a[lbl] - m - logf(sum));
  __shared__ float red[256];
  red[threadIdx.x] = ce;
  __syncthreads();
  for (int s = 128; s > 0; s >>= 1) {
    if (threadIdx.x < s) red[threadIdx.x] += red[threadIdx.x + s];
    __syncthreads();
  }
  if (threadIdx.x == 0) l1p[blockIdx.x] = red[0];
}

// world model: [obs(128), am(128)] -> 256 relu -> 128 ; LDS buffer aliased (wave-local rows)
__global__ __launch_bounds__(256) void k_wm(
    const float* __restrict__ obs, const float* __restrict__ act,
    const float* __restrict__ ws, const float* __restrict__ b1,
    const float* __restrict__ b2, float* __restrict__ onh)
{
  __shared__ __align__(16) float buf[32 * 256];   // inputs, then hid (per-wave rows)
  __shared__ __align__(16) float act_s[4 * 128];
  int tid = threadIdx.x, w = tid >> 6, lane = tid & 63;
  int row0 = blockIdx.x * 32, e0 = row0 >> 3;
  for (int i = tid; i < 512; i += 256) act_s[i] = act[(size_t)e0 * 128 + i];
  __syncthreads();
  for (int i = tid; i < 4096; i += 256) {
    int r = i >> 7, c = i & 127;
    buf[r * 256 + c] = obs[(size_t)row0 * 128 + i];
    int j = c >> 4, ii = r & 7;
    buf[r * 256 + 128 + c] = (j == ii) ? 0.f : act_s[(r >> 3) * 128 + c];
  }
  __syncthreads();
  const float* w1T = ws + T_WM1;
  const float* w2T = ws + T_WM2;
  float acc[8][4];
#pragma unroll
  for (int r = 0; r < 8; r++)
#pragma unroll
    for (int q = 0; q < 4; q++) acc[r][q] = b1[q * 64 + lane];
  for (int k = 0; k < 256; k += 4) {
    float b[4][4];
#pragma unroll
    for (int j = 0; j < 4; j++)
#pragma unroll
      for (int q = 0; q < 4; q++) b[j][q] = w1T[(k + j) * 256 + q * 64 + lane];
#pragma unroll
    for (int r = 0; r < 8; r++) {
      float4 a = LD4(buf + (w * 8 + r) * 256 + k);
#pragma unroll
      for (int q = 0; q < 4; q++)
        acc[r][q] = fmaf(a.x, b[0][q], fmaf(a.y, b[1][q], fmaf(a.z, b[2][q], fmaf(a.w, b[3][q], acc[r][q]))));
    }
  }
  // overwrite own rows with hidden (wave-local: safe without cross-wave sync)
#pragma unroll
  for (int r = 0; r < 8; r++)
#pragma unroll
    for (int q = 0; q < 4; q++)
      buf[(w * 8 + r) * 256 + q * 64 + lane] = fmaxf(acc[r][q], 0.f);
  __syncthreads();
  float c0[8], c1[8];
#pragma unroll
  for (int r = 0; r < 8; r++) { c0[r] = b2[lane]; c1[r] = b2[64 + lane]; }
  for (int k = 0; k < 256; k += 4) {
    float b0[4], b1_[4];
#pragma unroll
    for (int j = 0; j < 4; j++) {
      b0[j]  = w2T[(k + j) * 128 + lane];
      b1_[j] = w2T[(k + j) * 128 + 64 + lane];
    }
#pragma unroll
    for (int r = 0; r < 8; r++) {
      float4 a = LD4(buf + (w * 8 + r) * 256 + k);
      c0[r] = fmaf(a.x, b0[0], fmaf(a.y, b0[1], fmaf(a.z, b0[2], fmaf(a.w, b0[3], c0[r]))));
      c1[r] = fmaf(a.x, b1_[0], fmaf(a.y, b1_[1], fmaf(a.z, b1_[2], fmaf(a.w, b1_[3], c1[r]))));
    }
  }
#pragma unroll
  for (int r = 0; r < 8; r++) {
    onh[(size_t)(row0 + w * 8 + r) * 128 + lane]      = c0[r];
    onh[(size_t)(row0 + w * 8 + r) * 128 + 64 + lane] = c1[r];
  }
}

__global__ __launch_bounds__(256) void k_mse(
    const float* __restrict__ onh, const float* __restrict__ obsn, float* __restrict__ l2p)
{
  size_t tid = blockIdx.x * 256 + threadIdx.x;
  float s = 0.f;
  for (size_t idx = tid; idx < (size_t)ROWS * 128; idx += (size_t)1024 * 256) {
    float d = onh[idx] - obsn[idx];
    s = fmaf(d, d, s);
  }
  __shared__ float red[256];
  red[threadIdx.x] = s;
  __syncthreads();
  for (int st = 128; st > 0; st >>= 1) {
    if (threadIdx.x < st) red[threadIdx.x] += red[threadIdx.x + st];
    __syncthreads();
  }
  if (threadIdx.x == 0) l2p[blockIdx.x] = red[0];
}

// query = [obs, o_next_hat] @ wqT + b
__global__ __launch_bounds__(256) void k_query(
    const float* __restrict__ obs, const float* __restrict__ onh,
    const float* __restrict__ ws, const float* __restrict__ bq, float* __restrict__ qry)
{
  __shared__ __align__(16) float in_s[32 * 256];
  int tid = threadIdx.x, w = tid >> 6, lane = tid & 63;
  int row0 = blockIdx.x * 32;
  for (int i = tid; i < 4096; i += 256) {
    int r = i >> 7, c = i & 127;
    in_s[r * 256 + c]       = obs[(size_t)row0 * 128 + i];
    in_s[r * 256 + 128 + c] = onh[(size_t)row0 * 128 + i];
  }
  __syncthreads();
  const float* wqT = ws + T_WQ;
  float acc[8];
#pragma unroll
  for (int r = 0; r < 8; r++) acc[r] = bq[lane];
  for (int k = 0; k < 256; k += 4) {
    float b[4];
#pragma unroll
    for (int j = 0; j < 4; j++) b[j] = wqT[(k + j) * 64 + lane];
#pragma unroll
    for (int r = 0; r < 8; r++) {
      float4 a = LD4(in_s + (w * 8 + r) * 256 + k);
      acc[r] = fmaf(a.x, b[0], fmaf(a.y, b[1], fmaf(a.z, b[2], fmaf(a.w, b[3], acc[r]))));
    }
  }
#pragma unroll
  for (int r = 0; r < 8; r++) qry[(size_t)(row0 + w * 8 + r) * 64 + lane] = acc[r];
}

// key_off = act_off @ wkT + b  (K=16)
__global__ __launch_bounds__(256) void k_key(
    const float* __restrict__ act, const float* __restrict__ ws,
    const float* __restrict__ bk, float* __restrict__ key)
{
  __shared__ __align__(16) float a_s[32 * 16];
  int tid = threadIdx.x, w = tid >> 6, lane = tid & 63;
  int row0 = blockIdx.x * 32;
  for (int i = tid; i < 512; i += 256) a_s[i] = act[(size_t)row0 * 16 + i];
  __syncthreads();
  const float* wkT = ws + T_WK;
  float acc[8];
#pragma unroll
  for (int r = 0; r < 8; r++) acc[r] = bk[lane];
  for (int k = 0; k < 16; k += 4) {
    float b[4];
#pragma unroll
    for (int j = 0; j < 4; j++) b[j] = wkT[(k + j) * 64 + lane];
#pragma unroll
    for (int r = 0; r < 8; r++) {
      float4 a = LD4(a_s + (w * 8 + r) * 16 + k);
      acc[r] = fmaf(a.x, b[0], fmaf(a.y, b[1], fmaf(a.z, b[2], fmaf(a.w, b[3], acc[r]))));
    }
  }
#pragma unroll
  for (int r = 0; r < 8; r++) key[(size_t)(row0 + w * 8 + r) * 64 + lane] = acc[r];
}

// value_off: [h(64), act_off(16)] -> 64 relu -> 16
__global__ __launch_bounds__(256) void k_value(
    const float* __restrict__ h, const float* __restrict__ act,
    const float* __restrict__ ws, const float* __restrict__ b1,
    const float* __restrict__ b2, float* __restrict__ val)
{
  __shared__ __align__(16) float in_s[32 * 80];
  __shared__ __align__(16) float hid_s[32 * 64];
  int tid = threadIdx.x, w = tid >> 6, lane = tid & 63;
  int row0 = blockIdx.x * 32;
  for (int i = tid; i < 2048; i += 256) {
    int r = i >> 6, c = i & 63;
    in_s[r * 80 + c] = h[(size_t)row0 * 64 + i];
  }
  for (int i = tid; i < 512; i += 256) {
    int r = i >> 4, c = i & 15;
    in_s[r * 80 + 64 + c] = act[(size_t)row0 * 16 + i];
  }
  __syncthreads();
  const float* w1T = ws + T_WV1;
  const float* w2T = ws + T_WV2;
  float acc[8];
#pragma unroll
  for (int r = 0; r < 8; r++) acc[r] = b1[lane];
  for (int k = 0; k < 80; k += 4) {
    float b[4];
#pragma unroll
    for (int j = 0; j < 4; j++) b[j] = w1T[(k + j) * 64 + lane];
#pragma unroll
    for (int r = 0; r < 8; r++) {
      float4 a = LD4(in_s + (w * 8 + r) * 80 + k);
      acc[r] = fmaf(a.x, b[0], fmaf(a.y, b[1], fmaf(a.z, b[2], fmaf(a.w, b[3], acc[r]))));
    }
  }
#pragma unroll
  for (int r = 0; r < 8; r++) hid_s[(w * 8 + r) * 64 + lane] = fmaxf(acc[r], 0.f);
  __syncthreads();
  int col = lane & 15, kq = lane >> 4;
  float a2[8] = {0, 0, 0, 0, 0, 0, 0, 0};
  for (int kk = 0; kk < 16; kk += 4) {
    int k = kq * 16 + kk;
    float b[4];
#pragma unroll
    for (int j = 0; j < 4; j++) b[j] = w2T[(k + j) * 16 + col];
#pragma unroll
    for (int r = 0; r < 8; r++) {
      float4 a = LD4(hid_s + (w * 8 + r) * 64 + k);
      a2[r] = fmaf(a.x, b[0], fmaf(a.y, b[1], fmaf(a.z, b[2], fmaf(a.w, b[3], a2[r]))));
    }
  }
#pragma unroll
  for (int r = 0; r < 8; r++) {
    a2[r] += __shfl_xor(a2[r], 16);
    a2[r] += __shfl_xor(a2[r], 32);
  }
  if (lane < 16)
#pragma unroll
    for (int r = 0; r < 8; r++)
      val[(size_t)(row0 + w * 8 + r) * 16 + col] = a2[r] + b2[col];
}

// attention + output: wave per row b=(e,i)
__global__ __launch_bounds__(256) void k_attn(
    const float* __restrict__ qry, const float* __restrict__ key,
    const float* __restrict__ val, float* __restrict__ qout)
{
  __shared__ float q_s[4][64];
  int w = threadIdx.x >> 6, lane = threadIdx.x & 63;
  int b = blockIdx.x * 4 + w;
  int i = b & 7, e = b >> 3;
  q_s[w][lane] = qry[(size_t)b * 64 + lane];
  __syncthreads();
  int j = lane >> 3, p = lane & 7;
  const float* krow = key + ((size_t)e * 8 + j) * 64;
  float acc = 0.f;
  for (int t = 0; t < 8; t++) {
    int d = p * 8 + t;
    acc = fmaf(q_s[w][d], krow[d], acc);
  }
  acc += __shfl_xor(acc, 1);
  acc += __shfl_xor(acc, 2);
  acc += __shfl_xor(acc, 4);
  float score = (j == i) ? -1e9f : acc * 0.125f;   // /sqrt(64)
  float sc[8];
  float m = -1e30f;
  for (int jj = 0; jj < 8; jj++) {
    sc[jj] = __shfl(score, jj * 8);
    m = fmaxf(m, sc[jj]);
  }
  float ssum = 0.f;
  for (int jj = 0; jj < 8; jj++) { sc[jj] = expf(sc[jj] - m); ssum += sc[jj]; }
  float inv = 1.f / ssum;
  int c = lane & 15, g = lane >> 4;
  const float* vbase = val + (size_t)e * 128;
  float outv = sc[g] * inv * vbase[g * 16 + c] + sc[g + 4] * inv * vbase[(g + 4) * 16 + c];
  outv += __shfl_xor(outv, 16);
  outv += __shfl_xor(outv, 32);
  if (lane < 16) qout[(size_t)b * 16 + lane] = outv;
}

__global__ __launch_bounds__(256) void k_losses(
    const float* __restrict__ l1p, const float* __restrict__ l2p, float* __restrict__ dout)
{
  __shared__ float red[256];
  int tid = threadIdx.x;
  float s1 = (tid < 64) ? l1p[tid] : 0.f;
  float s2 = 0.f;
  for (int i = tid; i < 1024; i += 256) s2 += l2p[i];
  red[tid] = s1;
  __syncthreads();
  for (int s = 128; s > 0; s >>= 1) {
    if (tid < s) red[tid] += red[tid + s];
    __syncthreads();
  }
  float S1 = red[0];
  __syncthreads();
  red[tid] = s2;
  __syncthreads();
  for (int s = 128; s > 0; s >>= 1) {
    if (tid < s) red[tid] += red[tid + s];
    __syncthreads();
  }
  if (tid == 0) {
    dout[DO_L1] = S1 * 7.f / 131072.f;      // TW = 1
    dout[DO_L2] = red[0] / 2097152.f;       // WW = 1
  }
}

extern "C" void kernel_launch(void* const* d_in, const int* in_sizes, int n_in,
                              void* d_out, int out_size, void* d_ws, size_t ws_size,
                              hipStream_t stream) {
  const float* inputs   = (const float*)d_in[0];
  const float* hidden   = (const float*)d_in[1];
  const float* obs      = (const float*)d_in[2];
  const float* obs_next = (const float*)d_in[3];
  const int*   u        = (const int*)d_in[4];
  const float* fc1_w = (const float*)d_in[5];   const float* fc1_b = (const float*)d_in[6];
  const float* wih   = (const float*)d_in[7];   const float* bih   = (const float*)d_in[8];
  const float* whh   = (const float*)d_in[9];   const float* bhh   = (const float*)d_in[10];
  const float* tm_w1 = (const float*)d_in[11];  const float* tm_b1 = (const float*)d_in[12];
  const float* tm_w2 = (const float*)d_in[13];  const float* tm_b2 = (const float*)d_in[14];
  const float* wm_w1 = (const float*)d_in[15];  const float* wm_b1 = (const float*)d_in[16];
  const float* wm_w2 = (const float*)d_in[17];  const float* wm_b2 = (const float*)d_in[18];
  const float* wq_w  = (const float*)d_in[19];  const float* wq_b  = (const float*)d_in[20];
  const float* wk_w  = (const float*)d_in[21];  const float* wk_b  = (const float*)d_in[22];
  const float* wv1_w = (const float*)d_in[23];  const float* wv1_b = (const float*)d_in[24];
  const float* wv2_w = (const float*)d_in[25];  const float* wv2_b = (const float*)d_in[26];

  float* ws   = (float*)d_ws;
  float* out  = (float*)d_out;
  float* hbuf = out + DO_H;

  TPtrs tp;
  const float* srcs[11] = {fc1_w, wih, whh, tm_w1, tm_w2, wm_w1, wm_w2, wq_w, wk_w, wv1_w, wv2_w};
  int Os[11]  = {64, 192, 192, 256, 16, 256, 128, 64, 64, 64, 16};
  int Ks[11]  = {152, 64, 64, 72, 256, 256, 256, 256, 16, 80, 64};
  int Ofs[11] = {T_FC1, T_WIH, T_WHH, T_TM1, T_TM2, T_WM1, T_WM2, T_WQ, T_WK, T_WV1, T_WV2};
  for (int i = 0; i < 11; i++) { tp.src[i] = srcs[i]; tp.O[i] = Os[i]; tp.K[i] = Ks[i]; tp.dstOff[i] = Ofs[i]; }

  dim3 blk(256);
  k_transpose<<<88, blk, 0, stream>>>(tp, ws);
  k_trunk<<<ROWS / 32, blk, 0, stream>>>(inputs, hidden, ws, fc1_b, bih, bhh, hbuf);
  k_tm<<<ROWS / 32, blk, 0, stream>>>(hbuf, ws, tm_b1, tm_b2, ws + O_ACT);
  k_ce<<<ROWS / 256, blk, 0, stream>>>(ws + O_ACT, u, ws + O_L1P);
  k_wm<<<ROWS / 32, blk, 0, stream>>>(obs, ws + O_ACT, ws, wm_b1, wm_b2, ws + O_ONH);
  k_mse<<<1024, blk, 0, stream>>>(ws + O_ONH, obs_next, ws + O_L2P);
  k_query<<<ROWS / 32, blk, 0, stream>>>(obs, ws + O_ONH, ws, wq_b, ws + O_QRY);
  k_key<<<ROWS / 32, blk, 0, stream>>>(ws + O_ACT, ws, wk_b, ws + O_KEY);
  k_value<<<ROWS / 32, blk, 0, stream>>>(hbuf, ws + O_ACT, ws, wv1_b, wv2_b, ws + O_VAL);
  k_attn<<<ROWS / 4, blk, 0, stream>>>(ws + O_QRY, ws + O_KEY, ws + O_VAL, out);
  k_losses<<<1, blk, 0, stream>>>(ws + O_L1P, ws + O_L2P, out);
}

// Round 3
// 143.649 us; speedup vs baseline: 2.9560x; 1.1941x over previous
//
#include <hip/hip_runtime.h>
#include <math.h>

#define E_NUM 2048
#define A_N   8
#define ROWS  (E_NUM*A_N)   // 16384
#define INPD  152

typedef __attribute__((ext_vector_type(8))) short bf16x8;
typedef __attribute__((ext_vector_type(4))) float f32x4;

__device__ __forceinline__ unsigned short f2bf(float x) {
  unsigned int u = __float_as_uint(x);
  return (unsigned short)((u + 0x7FFFu + ((u >> 16) & 1u)) >> 16);
}
#define MFMA16(a,b,c) __builtin_amdgcn_mfma_f32_16x16x32_bf16(a,b,c,0,0,0)

// ---- ws layout (float offsets) ----
#define T_FC1 0          // 152*64 = 9728 (f32 transposed)
#define T_WIH 9728       // 64*192 = 12288
#define T_WHH 22016      // 64*192 = 12288
#define T_WK  34304      // 16*64  = 1024
#define T_WV1 35328      // 80*64  = 5120
#define T_WV2 40448      // 64*16  = 1024
#define TMB   41472      // 8*256 = 2048 (f32: tm_b1[o] + tm_w1[o][64+j])
#define B_WM1 43520      // 256x256 bf16 frag-major = 32768 floats
#define B_WM2 76288      // 128x256 bf16 = 16384
#define B_WQ  92672      // 64x256 bf16 = 8192
#define B_TM1 100864     // 256x64 bf16 = 8192
#define B_TM2 109056     // 16x256 bf16 = 2048
#define O_ACT 111104     // 16384*16 f32 (act_off[e*8+j][16])
#define O_ONH 373248     // 16384*128 f32
#define O_QRY 2470400    // 16384*64
#define O_KEY 3518976    // 16384*64
#define O_VAL 4567552    // 16384*16
#define O_L1P 4829696    // 64
#define O_L2P 4829760    // 1024

// d_out: q_reflect [0,262144) ; h ; loss1 ; loss2
#define DO_H   262144
#define DO_L1  1310720
#define DO_L2  1310721

#define LD4(p) (*(const float4*)(p))

struct TPtrs {
  const float* src[6];
  int O[6];
  int K[6];
  int dstOff[6];
};

// 8 blocks per matrix: WT[k*O+o] = W[o*K+k]  (f32, small matrices)
__global__ __launch_bounds__(256) void k_transpose(TPtrs p, float* __restrict__ ws) {
  int b = blockIdx.x >> 3, sl = blockIdx.x & 7;
  const float* s = p.src[b];
  float* d = ws + p.dstOff[b];
  int O = p.O[b], K = p.K[b], n = O * K;
  for (int i = sl * 256 + threadIdx.x; i < n; i += 2048) {
    int o = i / K, k = i - o * K;
    d[k * O + o] = s[i];
  }
}

struct SwzP {
  const float* src[5];
  int O[5];
  int K[5];
  int stride[5];
  int dstOff[5];   // in ushort units from (ushort*)ws
};

// bf16 frag-major swizzle: dst[((c*S+s)*64+l)*8+j] = bf16(W[c*16+(l&15)][s*32+(l>>4)*8+j])
__global__ __launch_bounds__(256) void k_swz(SwzP p, unsigned short* __restrict__ wsu) {
  int m = blockIdx.x >> 6, sub = blockIdx.x & 63;
  const float* src = p.src[m];
  unsigned short* dst = wsu + p.dstOff[m];
  int K = p.K[m], stride = p.stride[m], n = p.O[m] * K, S = K >> 5;
  for (int f = sub * 256 + threadIdx.x; f < n; f += 64 * 256) {
    int j = f & 7, l = (f >> 3) & 63, rest = f >> 9;
    int s = rest % S, c = rest / S;
    int row = c * 16 + (l & 15), col = s * 32 + ((l >> 4) << 3) + j;
    dst[f] = f2bf(src[row * stride + col]);
  }
}

// tmB[j][o] = tm_b1[o] + tm_w1[o][64+j]
__global__ __launch_bounds__(256) void k_tmb(
    const float* __restrict__ w1, const float* __restrict__ b1, float* __restrict__ tmB) {
  int i = blockIdx.x * 256 + threadIdx.x;   // 2048
  int j = i >> 8, o = i & 255;
  tmB[i] = b1[o] + w1[o * 72 + 64 + j];
}

// fused fc1 + GRU: 32 rows/block, 8 rows/wave (f32)
__global__ __launch_bounds__(256) void k_trunk(
    const float* __restrict__ inp, const float* __restrict__ hin,
    const float* __restrict__ ws, const float* __restrict__ fc1b,
    const float* __restrict__ bih, const float* __restrict__ bhh,
    float* __restrict__ hout)
{
  __shared__ __align__(16) float in_s[32 * INPD];
  __shared__ __align__(16) float x_s[32 * 64];
  __shared__ __align__(16) float h_s[32 * 64];
  int tid = threadIdx.x, w = tid >> 6, lane = tid & 63;
  int row0 = blockIdx.x * 32;
  for (int i = tid; i < 32 * INPD; i += 256) in_s[i] = inp[(size_t)row0 * INPD + i];
  for (int i = tid; i < 32 * 64;   i += 256) h_s[i]  = hin[(size_t)row0 * 64 + i];
  __syncthreads();
  const float* fc1T = ws + T_FC1;
  const float* wihT = ws + T_WIH;
  const float* whhT = ws + T_WHH;
  float acc[8];
#pragma unroll
  for (int r = 0; r < 8; r++) acc[r] = fc1b[lane];
  for (int k = 0; k < INPD; k += 4) {
    float b0 = fc1T[k * 64 + lane], b1 = fc1T[(k + 1) * 64 + lane];
    float b2 = fc1T[(k + 2) * 64 + lane], b3 = fc1T[(k + 3) * 64 + lane];
#pragma unroll
    for (int r = 0; r < 8; r++) {
      float4 a = LD4(in_s + (w * 8 + r) * INPD + k);
      acc[r] = fmaf(a.x, b0, fmaf(a.y, b1, fmaf(a.z, b2, fmaf(a.w, b3, acc[r]))));
    }
  }
#pragma unroll
  for (int r = 0; r < 8; r++) x_s[(w * 8 + r) * 64 + lane] = fmaxf(acc[r], 0.f);
  __syncthreads();
  float sr[8], sz[8], si[8], sh[8];
  float br = bih[lane] + bhh[lane], bz = bih[64 + lane] + bhh[64 + lane];
  float bin = bih[128 + lane], bhn = bhh[128 + lane];
#pragma unroll
  for (int r = 0; r < 8; r++) { sr[r] = br; sz[r] = bz; si[r] = bin; sh[r] = bhn; }
  for (int k = 0; k < 64; k += 4) {
    float bi0[4], bi1[4], bi2[4], bh0[4], bh1[4], bh2[4];
#pragma unroll
    for (int j = 0; j < 4; j++) {
      bi0[j] = wihT[(k + j) * 192 + lane];
      bi1[j] = wihT[(k + j) * 192 + 64 + lane];
      bi2[j] = wihT[(k + j) * 192 + 128 + lane];
      bh0[j] = whhT[(k + j) * 192 + lane];
      bh1[j] = whhT[(k + j) * 192 + 64 + lane];
      bh2[j] = whhT[(k + j) * 192 + 128 + lane];
    }
#pragma unroll
    for (int r = 0; r < 8; r++) {
      float4 xv = LD4(x_s + (w * 8 + r) * 64 + k);
      float4 hv = LD4(h_s + (w * 8 + r) * 64 + k);
      sr[r] = fmaf(xv.x, bi0[0], fmaf(xv.y, bi0[1], fmaf(xv.z, bi0[2], fmaf(xv.w, bi0[3], sr[r]))));
      sr[r] = fmaf(hv.x, bh0[0], fmaf(hv.y, bh0[1], fmaf(hv.z, bh0[2], fmaf(hv.w, bh0[3], sr[r]))));
      sz[r] = fmaf(xv.x, bi1[0], fmaf(xv.y, bi1[1], fmaf(xv.z, bi1[2], fmaf(xv.w, bi1[3], sz[r]))));
      sz[r] = fmaf(hv.x, bh1[0], fmaf(hv.y, bh1[1], fmaf(hv.z, bh1[2], fmaf(hv.w, bh1[3], sz[r]))));
      si[r] = fmaf(xv.x, bi2[0], fmaf(xv.y, bi2[1], fmaf(xv.z, bi2[2], fmaf(xv.w, bi2[3], si[r]))));
      sh[r] = fmaf(hv.x, bh2[0], fmaf(hv.y, bh2[1], fmaf(hv.z, bh2[2], fmaf(hv.w, bh2[3], sh[r]))));
    }
  }
#pragma unroll
  for (int r = 0; r < 8; r++) {
    float rg = 1.f / (1.f + expf(-sr[r]));
    float zg = 1.f / (1.f + expf(-sz[r]));
    float ng = tanhf(fmaf(rg, sh[r], si[r]));
    float h0 = h_s[(w * 8 + r) * 64 + lane];
    hout[(size_t)(row0 + w * 8 + r) * 64 + lane] = (1.f - zg) * ng + zg * h0;
  }
}

// teammate MLP (MFMA): [h(64)] -> 256 relu (+tmB[j]) -> 16 ; 64 rows/block, 16/wave
__global__ __launch_bounds__(256) void k_tm(
    const float* __restrict__ h,
    const unsigned short* __restrict__ w1b, const unsigned short* __restrict__ w2b,
    const float* __restrict__ tmB, const float* __restrict__ b2,
    float* __restrict__ act)
{
  __shared__ __align__(16) unsigned short in_s[64 * 72];    // stride 72 (16B aligned rows)
  __shared__ __align__(16) unsigned short hid_s[64 * 264];  // stride 264
  int tid = threadIdx.x, w = tid >> 6, lane = tid & 63;
  int row0 = blockIdx.x * 64;
  for (int i = tid; i < 64 * 64; i += 256) {
    int r = i >> 6, c = i & 63;
    in_s[r * 72 + c] = f2bf(h[(size_t)(row0 + r) * 64 + c]);
  }
  __syncthreads();
  int rbase = w * 16;
  // layer1: N=256 (c=0..15), K=64 (s=0,1)
  f32x4 acc[16];
#pragma unroll
  for (int c = 0; c < 16; c++) acc[c] = {0.f, 0.f, 0.f, 0.f};
#pragma unroll
  for (int s = 0; s < 2; s++) {
    bf16x8 af = *(const bf16x8*)(in_s + (rbase + (lane & 15)) * 72 + s * 32 + ((lane >> 4) << 3));
#pragma unroll
    for (int c = 0; c < 16; c++) {
      bf16x8 bf = *(const bf16x8*)(w1b + (size_t)((c * 2 + s) * 64 + lane) * 8);
      acc[c] = MFMA16(af, bf, acc[c]);
    }
  }
#pragma unroll
  for (int c = 0; c < 16; c++)
#pragma unroll
    for (int r = 0; r < 4; r++) {
      int drow = ((lane >> 4) << 2) + r;
      int col = c * 16 + (lane & 15);
      float v = acc[c][r] + tmB[(drow & 7) * 256 + col];
      hid_s[(rbase + drow) * 264 + col] = f2bf(fmaxf(v, 0.f));
    }
  __syncthreads();
  // layer2: N=16, K=256 (s=0..7)
  f32x4 a2 = {0.f, 0.f, 0.f, 0.f};
#pragma unroll
  for (int s = 0; s < 8; s++) {
    bf16x8 af = *(const bf16x8*)(hid_s + (rbase + (lane & 15)) * 264 + s * 32 + ((lane >> 4) << 3));
    bf16x8 bf = *(const bf16x8*)(w2b + (size_t)(s * 64 + lane) * 8);
    a2 = MFMA16(af, bf, a2);
  }
#pragma unroll
  for (int r = 0; r < 4; r++) {
    int drow = ((lane >> 4) << 2) + r;
    act[(size_t)(row0 + rbase + drow) * 16 + (lane & 15)] = a2[r] + b2[lane & 15];
  }
}

__global__ __launch_bounds__(256) void k_ce(
    const float* __restrict__ act, const int* __restrict__ u, float* __restrict__ l1p)
{
  int tid = blockIdx.x * 256 + threadIdx.x;
  const float* a = act + (size_t)tid * 16;
  float m = a[0];
  for (int c = 1; c < 16; c++) m = fmaxf(m, a[c]);
  float sum = 0.f;
  for (int c = 0; c < 16; c++) sum += expf(a[c] - m);
  int lbl = u[tid];
  float ce = -(a[lbl] - m - logf(sum));
  __shared__ float red[256];
  red[threadIdx.x] = ce;
  __syncthreads();
  for (int s = 128; s > 0; s >>= 1) {
    if (threadIdx.x < s) red[threadIdx.x] += red[threadIdx.x + s];
    __syncthreads();
  }
  if (threadIdx.x == 0) l1p[blockIdx.x] = red[0];
}

// world model (MFMA): [obs(128) bf16 | masked act(128) bf16] -> 256 relu -> 128
__global__ __launch_bounds__(256) void k_wm(
    const float* __restrict__ obs, const float* __restrict__ act,
    const unsigned short* __restrict__ w1b, const unsigned short* __restrict__ w2b,
    const float* __restrict__ b1, const float* __restrict__ b2,
    float* __restrict__ onh)
{
  __shared__ __align__(16) unsigned short in_s[64 * 264];   // input, then hid (aliased)
  __shared__ __align__(16) unsigned short act_bs[8 * 128];
  int tid = threadIdx.x, w = tid >> 6, lane = tid & 63;
  int row0 = blockIdx.x * 64, e0 = row0 >> 3;
  for (int i = tid; i < 1024; i += 256) act_bs[i] = f2bf(act[(size_t)e0 * 128 + i]);
  for (int i = tid; i < 64 * 128; i += 256) {
    int r = i >> 7, c = i & 127;
    in_s[r * 264 + c] = f2bf(obs[(size_t)(row0 + r) * 128 + c]);
  }
  __syncthreads();
  for (int i = tid; i < 64 * 128; i += 256) {
    int r = i >> 7, c = i & 127;
    int ii = r & 7, e = r >> 3;
    in_s[r * 264 + 128 + c] = ((c >> 4) == ii) ? (unsigned short)0 : act_bs[e * 128 + c];
  }
  __syncthreads();
  int rbase = w * 16;
  // layer1: N=256 (c 0..15), K=256 (s 0..7)
  f32x4 acc[16];
#pragma unroll
  for (int c = 0; c < 16; c++) acc[c] = {0.f, 0.f, 0.f, 0.f};
  for (int s = 0; s < 8; s++) {
    bf16x8 af = *(const bf16x8*)(in_s + (rbase + (lane & 15)) * 264 + s * 32 + ((lane >> 4) << 3));
#pragma unroll
    for (int c = 0; c < 16; c++) {
      bf16x8 bf = *(const bf16x8*)(w1b + (size_t)((c * 8 + s) * 64 + lane) * 8);
      acc[c] = MFMA16(af, bf, acc[c]);
    }
  }
  // hid -> own rows of in_s (wave-local reads above, so overwrite is safe)
#pragma unroll
  for (int c = 0; c < 16; c++)
#pragma unroll
    for (int r = 0; r < 4; r++) {
      int drow = ((lane >> 4) << 2) + r;
      int col = c * 16 + (lane & 15);
      in_s[(rbase + drow) * 264 + col] = f2bf(fmaxf(acc[c][r] + b1[col], 0.f));
    }
  __syncthreads();
  // layer2: N=128 (c 0..7), K=256
  f32x4 a2[8];
#pragma unroll
  for (int c = 0; c < 8; c++) a2[c] = {0.f, 0.f, 0.f, 0.f};
  for (int s = 0; s < 8; s++) {
    bf16x8 af = *(const bf16x8*)(in_s + (rbase + (lane & 15)) * 264 + s * 32 + ((lane >> 4) << 3));
#pragma unroll
    for (int c = 0; c < 8; c++) {
      bf16x8 bf = *(const bf16x8*)(w2b + (size_t)((c * 8 + s) * 64 + lane) * 8);
      a2[c] = MFMA16(af, bf, a2[c]);
    }
  }
#pragma unroll
  for (int c = 0; c < 8; c++)
#pragma unroll
    for (int r = 0; r < 4; r++) {
      int drow = ((lane >> 4) << 2) + r;
      int col = c * 16 + (lane & 15);
      onh[(size_t)(row0 + rbase + drow) * 128 + col] = a2[c][r] + b2[col];
    }
}

__global__ __launch_bounds__(256) void k_mse(
    const float* __restrict__ onh, const float* __restrict__ obsn, float* __restrict__ l2p)
{
  size_t tid = blockIdx.x * 256 + threadIdx.x;
  float s = 0.f;
  for (size_t idx = tid; idx < (size_t)ROWS * 128; idx += (size_t)1024 * 256) {
    float d = onh[idx] - obsn[idx];
    s = fmaf(d, d, s);
  }
  __shared__ float red[256];
  red[threadIdx.x] = s;
  __syncthreads();
  for (int st = 128; st > 0; st >>= 1) {
    if (threadIdx.x < st) red[threadIdx.x] += red[threadIdx.x + st];
    __syncthreads();
  }
  if (threadIdx.x == 0) l2p[blockIdx.x] = red[0];
}

// query (MFMA): [obs|onh] (256) -> 64
__global__ __launch_bounds__(256) void k_query(
    const float* __restrict__ obs, const float* __restrict__ onh,
    const unsigned short* __restrict__ wqb, const float* __restrict__ bq,
    float* __restrict__ qry)
{
  __shared__ __align__(16) unsigned short in_s[64 * 264];
  int tid = threadIdx.x, w = tid >> 6, lane = tid & 63;
  int row0 = blockIdx.x * 64;
  for (int i = tid; i < 64 * 128; i += 256) {
    int r = i >> 7, c = i & 127;
    in_s[r * 264 + c]       = f2bf(obs[(size_t)(row0 + r) * 128 + c]);
    in_s[r * 264 + 128 + c] = f2bf(onh[(size_t)(row0 + r) * 128 + c]);
  }
  __syncthreads();
  int rbase = w * 16;
  f32x4 acc[4];
#pragma unroll
  for (int c = 0; c < 4; c++) acc[c] = {0.f, 0.f, 0.f, 0.f};
  for (int s = 0; s < 8; s++) {
    bf16x8 af = *(const bf16x8*)(in_s + (rbase + (lane & 15)) * 264 + s * 32 + ((lane >> 4) << 3));
#pragma unroll
    for (int c = 0; c < 4; c++) {
      bf16x8 bf = *(const bf16x8*)(wqb + (size_t)((c * 8 + s) * 64 + lane) * 8);
      acc[c] = MFMA16(af, bf, acc[c]);
    }
  }
#pragma unroll
  for (int c = 0; c < 4; c++)
#pragma unroll
    for (int r = 0; r < 4; r++) {
      int drow = ((lane >> 4) << 2) + r;
      int col = c * 16 + (lane & 15);
      qry[(size_t)(row0 + rbase + drow) * 64 + col] = acc[c][r] + bq[col];
    }
}

// key_off = act_off @ wkT + b  (K=16, f32)
__global__ __launch_bounds__(256) void k_key(
    const float* __restrict__ act, const float* __restrict__ ws,
    const float* __restrict__ bk, float* __restrict__ key)
{
  __shared__ __align__(16) float a_s[32 * 16];
  int tid = threadIdx.x, w = tid >> 6, lane = tid & 63;
  int row0 = blockIdx.x * 32;
  for (int i = tid; i < 512; i += 256) a_s[i] = act[(size_t)row0 * 16 + i];
  __syncthreads();
  const float* wkT = ws + T_WK;
  float acc[8];
#pragma unroll
  for (int r = 0; r < 8; r++) acc[r] = bk[lane];
  for (int k = 0; k < 16; k += 4) {
    float b[4];
#pragma unroll
    for (int j = 0; j < 4; j++) b[j] = wkT[(k + j) * 64 + lane];
#pragma unroll
    for (int r = 0; r < 8; r++) {
      float4 a = LD4(a_s + (w * 8 + r) * 16 + k);
      acc[r] = fmaf(a.x, b[0], fmaf(a.y, b[1], fmaf(a.z, b[2], fmaf(a.w, b[3], acc[r]))));
    }
  }
#pragma unroll
  for (int r = 0; r < 8; r++) key[(size_t)(row0 + w * 8 + r) * 64 + lane] = acc[r];
}

// value_off: [h(64), act_off(16)] -> 64 relu -> 16 (f32)
__global__ __launch_bounds__(256) void k_value(
    const float* __restrict__ h, const float* __restrict__ act,
    const float* __restrict__ ws, const float* __restrict__ b1,
    const float* __restrict__ b2, float* __restrict__ val)
{
  __shared__ __align__(16) float in_s[32 * 80];
  __shared__ __align__(16) float hid_s[32 * 64];
  int tid = threadIdx.x, w = tid >> 6, lane = tid & 63;
  int row0 = blockIdx.x * 32;
  for (int i = tid; i < 2048; i += 256) {
    int r = i >> 6, c = i & 63;
    in_s[r * 80 + c] = h[(size_t)row0 * 64 + i];
  }
  for (int i = tid; i < 512; i += 256) {
    int r = i >> 4, c = i & 15;
    in_s[r * 80 + 64 + c] = act[(size_t)row0 * 16 + i];
  }
  __syncthreads();
  const float* w1T = ws + T_WV1;
  const float* w2T = ws + T_WV2;
  float acc[8];
#pragma unroll
  for (int r = 0; r < 8; r++) acc[r] = b1[lane];
  for (int k = 0; k < 80; k += 4) {
    float b[4];
#pragma unroll
    for (int j = 0; j < 4; j++) b[j] = w1T[(k + j) * 64 + lane];
#pragma unroll
    for (int r = 0; r < 8; r++) {
      float4 a = LD4(in_s + (w * 8 + r) * 80 + k);
      acc[r] = fmaf(a.x, b[0], fmaf(a.y, b[1], fmaf(a.z, b[2], fmaf(a.w, b[3], acc[r]))));
    }
  }
#pragma unroll
  for (int r = 0; r < 8; r++) hid_s[(w * 8 + r) * 64 + lane] = fmaxf(acc[r], 0.f);
  __syncthreads();
  int col = lane & 15, kq = lane >> 4;
  float a2[8] = {0, 0, 0, 0, 0, 0, 0, 0};
  for (int kk = 0; kk < 16; kk += 4) {
    int k = kq * 16 + kk;
    float b[4];
#pragma unroll
    for (int j = 0; j < 4; j++) b[j] = w2T[(k + j) * 16 + col];
#pragma unroll
    for (int r = 0; r < 8; r++) {
      float4 a = LD4(hid_s + (w * 8 + r) * 64 + k);
      a2[r] = fmaf(a.x, b[0], fmaf(a.y, b[1], fmaf(a.z, b[2], fmaf(a.w, b[3], a2[r]))));
    }
  }
#pragma unroll
  for (int r = 0; r < 8; r++) {
    a2[r] += __shfl_xor(a2[r], 16);
    a2[r] += __shfl_xor(a2[r], 32);
  }
  if (lane < 16)
#pragma unroll
    for (int r = 0; r < 8; r++)
      val[(size_t)(row0 + w * 8 + r) * 16 + col] = a2[r] + b2[col];
}

// attention + output: wave per row b=(e,i)
__global__ __launch_bounds__(256) void k_attn(
    const float* __restrict__ qry, const float* __restrict__ key,
    const float* __restrict__ val, float* __restrict__ qout)
{
  __shared__ float q_s[4][64];
  int w = threadIdx.x >> 6, lane = threadIdx.x & 63;
  int b = blockIdx.x * 4 + w;
  int i = b & 7, e = b >> 3;
  q_s[w][lane] = qry[(size_t)b * 64 + lane];
  __syncthreads();
  int j = lane >> 3, p = lane & 7;
  const float* krow = key + ((size_t)e * 8 + j) * 64;
  float acc = 0.f;
  for (int t = 0; t < 8; t++) {
    int d = p * 8 + t;
    acc = fmaf(q_s[w][d], krow[d], acc);
  }
  acc += __shfl_xor(acc, 1);
  acc += __shfl_xor(acc, 2);
  acc += __shfl_xor(acc, 4);
  float score = (j == i) ? -1e9f : acc * 0.125f;
  float sc[8];
  float m = -1e30f;
  for (int jj = 0; jj < 8; jj++) {
    sc[jj] = __shfl(score, jj * 8);
    m = fmaxf(m, sc[jj]);
  }
  float ssum = 0.f;
  for (int jj = 0; jj < 8; jj++) { sc[jj] = expf(sc[jj] - m); ssum += sc[jj]; }
  float inv = 1.f / ssum;
  int c = lane & 15, g = lane >> 4;
  const float* vbase = val + (size_t)e * 128;
  float outv = sc[g] * inv * vbase[g * 16 + c] + sc[g + 4] * inv * vbase[(g + 4) * 16 + c];
  outv += __shfl_xor(outv, 16);
  outv += __shfl_xor(outv, 32);
  if (lane < 16) qout[(size_t)b * 16 + lane] = outv;
}

__global__ __launch_bounds__(256) void k_losses(
    const float* __restrict__ l1p, const float* __restrict__ l2p, float* __restrict__ dout)
{
  __shared__ float red[256];
  int tid = threadIdx.x;
  float s1 = (tid < 64) ? l1p[tid] : 0.f;
  float s2 = 0.f;
  for (int i = tid; i < 1024; i += 256) s2 += l2p[i];
  red[tid] = s1;
  __syncthreads();
  for (int s = 128; s > 0; s >>= 1) {
    if (tid < s) red[tid] += red[tid + s];
    __syncthreads();
  }
  float S1 = red[0];
  __syncthreads();
  red[tid] = s2;
  __syncthreads();
  for (int s = 128; s > 0; s >>= 1) {
    if (tid < s) red[tid] += red[tid + s];
    __syncthreads();
  }
  if (tid == 0) {
    dout[DO_L1] = S1 * 7.f / 131072.f;
    dout[DO_L2] = red[0] / 2097152.f;
  }
}

extern "C" void kernel_launch(void* const* d_in, const int* in_sizes, int n_in,
                              void* d_out, int out_size, void* d_ws, size_t ws_size,
                              hipStream_t stream) {
  const float* inputs   = (const float*)d_in[0];
  const float* hidden   = (const float*)d_in[1];
  const float* obs      = (const float*)d_in[2];
  const float* obs_next = (const float*)d_in[3];
  const int*   u        = (const int*)d_in[4];
  const float* fc1_w = (const float*)d_in[5];   const float* fc1_b = (const float*)d_in[6];
  const float* wih   = (const float*)d_in[7];   const float* bih   = (const float*)d_in[8];
  const float* whh   = (const float*)d_in[9];   const float* bhh   = (const float*)d_in[10];
  const float* tm_w1 = (const float*)d_in[11];  const float* tm_b1 = (const float*)d_in[12];
  const float* tm_w2 = (const float*)d_in[13];  const float* tm_b2 = (const float*)d_in[14];
  const float* wm_w1 = (const float*)d_in[15];  const float* wm_b1 = (const float*)d_in[16];
  const float* wm_w2 = (const float*)d_in[17];  const float* wm_b2 = (const float*)d_in[18];
  const float* wq_w  = (const float*)d_in[19];  const float* wq_b  = (const float*)d_in[20];
  const float* wk_w  = (const float*)d_in[21];  const float* wk_b  = (const float*)d_in[22];
  const float* wv1_w = (const float*)d_in[23];  const float* wv1_b = (const float*)d_in[24];
  const float* wv2_w = (const float*)d_in[25];  const float* wv2_b = (const float*)d_in[26];

  float* ws   = (float*)d_ws;
  unsigned short* wsu = (unsigned short*)d_ws;
  float* out  = (float*)d_out;
  float* hbuf = out + DO_H;

  TPtrs tp;
  const float* srcs[6] = {fc1_w, wih, whh, wk_w, wv1_w, wv2_w};
  int Os[6]  = {64, 192, 192, 64, 64, 16};
  int Ks[6]  = {152, 64, 64, 16, 80, 64};
  int Ofs[6] = {T_FC1, T_WIH, T_WHH, T_WK, T_WV1, T_WV2};
  for (int i = 0; i < 6; i++) { tp.src[i] = srcs[i]; tp.O[i] = Os[i]; tp.K[i] = Ks[i]; tp.dstOff[i] = Ofs[i]; }

  SwzP sp;
  const float* ssrc[5] = {wm_w1, wm_w2, wq_w, tm_w1, tm_w2};
  int sO[5]  = {256, 128, 64, 256, 16};
  int sK[5]  = {256, 256, 256, 64, 256};
  int sSt[5] = {256, 256, 256, 72, 256};
  int sOf[5] = {B_WM1 * 2, B_WM2 * 2, B_WQ * 2, B_TM1 * 2, B_TM2 * 2};
  for (int i = 0; i < 5; i++) { sp.src[i] = ssrc[i]; sp.O[i] = sO[i]; sp.K[i] = sK[i]; sp.stride[i] = sSt[i]; sp.dstOff[i] = sOf[i]; }

  dim3 blk(256);
  k_transpose<<<48, blk, 0, stream>>>(tp, ws);
  k_swz<<<320, blk, 0, stream>>>(sp, wsu);
  k_tmb<<<8, blk, 0, stream>>>(tm_w1, tm_b1, ws + TMB);
  k_trunk<<<ROWS / 32, blk, 0, stream>>>(inputs, hidden, ws, fc1_b, bih, bhh, hbuf);
  k_tm<<<ROWS / 64, blk, 0, stream>>>(hbuf, wsu + B_TM1 * 2, wsu + B_TM2 * 2, ws + TMB, tm_b2, ws + O_ACT);
  k_ce<<<ROWS / 256, blk, 0, stream>>>(ws + O_ACT, u, ws + O_L1P);
  k_wm<<<ROWS / 64, blk, 0, stream>>>(obs, ws + O_ACT, wsu + B_WM1 * 2, wsu + B_WM2 * 2, wm_b1, wm_b2, ws + O_ONH);
  k_mse<<<1024, blk, 0, stream>>>(ws + O_ONH, obs_next, ws + O_L2P);
  k_query<<<ROWS / 64, blk, 0, stream>>>(obs, ws + O_ONH, wsu + B_WQ * 2, wq_b, ws + O_QRY);
  k_key<<<ROWS / 32, blk, 0, stream>>>(ws + O_ACT, ws, wk_b, ws + O_KEY);
  k_value<<<ROWS / 32, blk, 0, stream>>>(hbuf, ws + O_ACT, ws, wv1_b, wv2_b, ws + O_VAL);
  k_attn<<<ROWS / 4, blk, 0, stream>>>(ws + O_QRY, ws + O_KEY, ws + O_VAL, out);
  k_losses<<<1, blk, 0, stream>>>(ws + O_L1P, ws + O_L2P, out);
}

// Round 4
// 79.782 us; speedup vs baseline: 5.3224x; 1.8005x over previous
//
#include <hip/hip_runtime.h>
#include <math.h>

#define E_NUM 2048
#define A_N   8
#define ROWS  (E_NUM*A_N)   // 16384
#define INPD  152

typedef __attribute__((ext_vector_type(8))) short bf16x8;
typedef __attribute__((ext_vector_type(4))) float f32x4;

__device__ __forceinline__ unsigned short f2bf(float x) {
  unsigned int u = __float_as_uint(x);
  return (unsigned short)((u + 0x7FFFu + ((u >> 16) & 1u)) >> 16);
}
#define MFMA16(a,b,c) __builtin_amdgcn_mfma_f32_16x16x32_bf16(a,b,c,0,0,0)

// ---- ws layout (float offsets) ----
#define T_FC1 0          // 152*64 f32 transposed
#define T_WIH 9728       // 64*192
#define T_WHH 22016      // 64*192
#define T_WK  34304      // 16*64
#define T_WV1 35328      // 80*64
#define T_WV2 40448      // 64*16
#define TMB   41472      // 8*256 f32: tm_b1[o] + tm_w1[o][64+j]
#define B_WM1 43520      // 256x256 bf16 frag-major (32768 floats)
#define B_WM2 76288      // 128x256 bf16
#define B_WQ  92672      // 64x256 bf16
#define B_TM1 100864     // 256x64 bf16
#define B_TM2 109056     // 16x256 bf16
#define O_ACT 111104     // 16384*16 f32
#define O_ONH 373248     // 16384*128 f32
#define O_QRY 2470400    // 16384*64 f32
#define O_L1P 4829696    // 256
#define O_L2P 4829952    // 256

// d_out: q_reflect [0,262144) ; h ; loss1 ; loss2
#define DO_H   262144
#define DO_L1  1310720
#define DO_L2  1310721

#define LD4(p) (*(const float4*)(p))

struct PrepP {
  const float* tsrc[6]; int tO[6], tK[6], tOff[6];
  const float* ssrc[5]; int sO[5], sK[5], sSt[5], sOff[5];
  const float* tm_w1; const float* tm_b1;
};

// blocks 0..47: f32 transpose ; 48..367: bf16 frag swizzle ; 368..375: tmB
__global__ __launch_bounds__(256) void k_prep(PrepP p, float* __restrict__ ws,
                                              unsigned short* __restrict__ wsu) {
  int bid = blockIdx.x;
  if (bid < 48) {
    int b = bid >> 3, sl = bid & 7;
    const float* s = p.tsrc[b];
    float* d = ws + p.tOff[b];
    int O = p.tO[b], K = p.tK[b], n = O * K;
    for (int i = sl * 256 + threadIdx.x; i < n; i += 2048) {
      int o = i / K, k = i - o * K;
      d[k * O + o] = s[i];
    }
  } else if (bid < 368) {
    int q = bid - 48, m = q >> 6, sub = q & 63;
    const float* src = p.ssrc[m];
    unsigned short* dst = wsu + p.sOff[m];
    int K = p.sK[m], stride = p.sSt[m], n = p.sO[m] * K, S = K >> 5;
    for (int f = sub * 256 + threadIdx.x; f < n; f += 64 * 256) {
      int j = f & 7, l = (f >> 3) & 63, rest = f >> 9;
      int s = rest % S, c = rest / S;
      int row = c * 16 + (l & 15), col = s * 32 + ((l >> 4) << 3) + j;
      dst[f] = f2bf(src[row * stride + col]);
    }
  } else {
    int i = (bid - 368) * 256 + threadIdx.x;  // 2048
    int j = i >> 8, o = i & 255;
    ws[TMB + i] = p.tm_b1[o] + p.tm_w1[o * 72 + 64 + j];
  }
}

// fused fc1 + GRU: 32 rows/block, 8 rows/wave (f32)
__global__ __launch_bounds__(256) void k_trunk(
    const float* __restrict__ inp, const float* __restrict__ hin,
    const float* __restrict__ ws, const float* __restrict__ fc1b,
    const float* __restrict__ bih, const float* __restrict__ bhh,
    float* __restrict__ hout)
{
  __shared__ __align__(16) float in_s[32 * INPD];
  __shared__ __align__(16) float x_s[32 * 64];
  __shared__ __align__(16) float h_s[32 * 64];
  int tid = threadIdx.x, w = tid >> 6, lane = tid & 63;
  int row0 = blockIdx.x * 32;
  for (int i = tid; i < 32 * INPD; i += 256) in_s[i] = inp[(size_t)row0 * INPD + i];
  for (int i = tid; i < 32 * 64;   i += 256) h_s[i]  = hin[(size_t)row0 * 64 + i];
  __syncthreads();
  const float* fc1T = ws + T_FC1;
  const float* wihT = ws + T_WIH;
  const float* whhT = ws + T_WHH;
  float acc[8];
#pragma unroll
  for (int r = 0; r < 8; r++) acc[r] = fc1b[lane];
  for (int k = 0; k < INPD; k += 4) {
    float b0 = fc1T[k * 64 + lane], b1 = fc1T[(k + 1) * 64 + lane];
    float b2 = fc1T[(k + 2) * 64 + lane], b3 = fc1T[(k + 3) * 64 + lane];
#pragma unroll
    for (int r = 0; r < 8; r++) {
      float4 a = LD4(in_s + (w * 8 + r) * INPD + k);
      acc[r] = fmaf(a.x, b0, fmaf(a.y, b1, fmaf(a.z, b2, fmaf(a.w, b3, acc[r]))));
    }
  }
#pragma unroll
  for (int r = 0; r < 8; r++) x_s[(w * 8 + r) * 64 + lane] = fmaxf(acc[r], 0.f);
  __syncthreads();
  float sr[8], sz[8], si[8], sh[8];
  float br = bih[lane] + bhh[lane], bz = bih[64 + lane] + bhh[64 + lane];
  float bin = bih[128 + lane], bhn = bhh[128 + lane];
#pragma unroll
  for (int r = 0; r < 8; r++) { sr[r] = br; sz[r] = bz; si[r] = bin; sh[r] = bhn; }
  for (int k = 0; k < 64; k += 4) {
    float bi0[4], bi1[4], bi2[4], bh0[4], bh1[4], bh2[4];
#pragma unroll
    for (int j = 0; j < 4; j++) {
      bi0[j] = wihT[(k + j) * 192 + lane];
      bi1[j] = wihT[(k + j) * 192 + 64 + lane];
      bi2[j] = wihT[(k + j) * 192 + 128 + lane];
      bh0[j] = whhT[(k + j) * 192 + lane];
      bh1[j] = whhT[(k + j) * 192 + 64 + lane];
      bh2[j] = whhT[(k + j) * 192 + 128 + lane];
    }
#pragma unroll
    for (int r = 0; r < 8; r++) {
      float4 xv = LD4(x_s + (w * 8 + r) * 64 + k);
      float4 hv = LD4(h_s + (w * 8 + r) * 64 + k);
      sr[r] = fmaf(xv.x, bi0[0], fmaf(xv.y, bi0[1], fmaf(xv.z, bi0[2], fmaf(xv.w, bi0[3], sr[r]))));
      sr[r] = fmaf(hv.x, bh0[0], fmaf(hv.y, bh0[1], fmaf(hv.z, bh0[2], fmaf(hv.w, bh0[3], sr[r]))));
      sz[r] = fmaf(xv.x, bi1[0], fmaf(xv.y, bi1[1], fmaf(xv.z, bi1[2], fmaf(xv.w, bi1[3], sz[r]))));
      sz[r] = fmaf(hv.x, bh1[0], fmaf(hv.y, bh1[1], fmaf(hv.z, bh1[2], fmaf(hv.w, bh1[3], sz[r]))));
      si[r] = fmaf(xv.x, bi2[0], fmaf(xv.y, bi2[1], fmaf(xv.z, bi2[2], fmaf(xv.w, bi2[3], si[r]))));
      sh[r] = fmaf(hv.x, bh2[0], fmaf(hv.y, bh2[1], fmaf(hv.z, bh2[2], fmaf(hv.w, bh2[3], sh[r]))));
    }
  }
#pragma unroll
  for (int r = 0; r < 8; r++) {
    float rg = 1.f / (1.f + expf(-sr[r]));
    float zg = 1.f / (1.f + expf(-sz[r]));
    float ng = tanhf(fmaf(rg, sh[r], si[r]));
    float h0 = h_s[(w * 8 + r) * 64 + lane];
    hout[(size_t)(row0 + w * 8 + r) * 64 + lane] = (1.f - zg) * ng + zg * h0;
  }
}

// teammate MLP + CE (MFMA, weight-stationary): 64 rows/block, 8 waves
__global__ __launch_bounds__(512) void k_tm(
    const float* __restrict__ h,
    const unsigned short* __restrict__ w1b, const unsigned short* __restrict__ w2b,
    const float* __restrict__ tmB, const float* __restrict__ b2,
    const int* __restrict__ u,
    float* __restrict__ act, float* __restrict__ l1p)
{
  __shared__ __align__(16) unsigned short in_s[64 * 72];
  __shared__ __align__(16) unsigned short hid_s[64 * 264];
  __shared__ float red[512];
  int tid = threadIdx.x, w = tid >> 6, lane = tid & 63;
  int lo = lane & 15, hi = lane >> 4;
  int row0 = blockIdx.x * 64;
  for (int i = tid; i < 4096; i += 512) {
    int r = i >> 6, c = i & 63;
    in_s[r * 72 + c] = f2bf(h[(size_t)(row0 + r) * 64 + c]);
  }
  bf16x8 wf1[2][2];
#pragma unroll
  for (int cc = 0; cc < 2; cc++)
#pragma unroll
    for (int s = 0; s < 2; s++)
      wf1[cc][s] = *(const bf16x8*)(w1b + (size_t)(((2 * w + cc) * 2 + s) * 64 + lane) * 8);
  __syncthreads();
  f32x4 acc[4][2];
#pragma unroll
  for (int rt = 0; rt < 4; rt++) { acc[rt][0] = {0,0,0,0}; acc[rt][1] = {0,0,0,0}; }
#pragma unroll
  for (int s = 0; s < 2; s++)
#pragma unroll
    for (int rt = 0; rt < 4; rt++) {
      bf16x8 af = *(const bf16x8*)(in_s + (rt * 16 + lo) * 72 + s * 32 + hi * 8);
      acc[rt][0] = MFMA16(af, wf1[0][s], acc[rt][0]);
      acc[rt][1] = MFMA16(af, wf1[1][s], acc[rt][1]);
    }
#pragma unroll
  for (int rt = 0; rt < 4; rt++)
#pragma unroll
    for (int r = 0; r < 4; r++) {
      int rowl = rt * 16 + hi * 4 + r, j = (hi * 4 + r) & 7;
      float v0 = acc[rt][0][r] + tmB[j * 256 + 32 * w + lo];
      float v1 = acc[rt][1][r] + tmB[j * 256 + 32 * w + 16 + lo];
      hid_s[rowl * 264 + 32 * w + lo]      = f2bf(fmaxf(v0, 0.f));
      hid_s[rowl * 264 + 32 * w + 16 + lo] = f2bf(fmaxf(v1, 0.f));
    }
  __syncthreads();
  float ces = 0.f;
  if (w < 4) {
    bf16x8 wf2[8];
#pragma unroll
    for (int s = 0; s < 8; s++)
      wf2[s] = *(const bf16x8*)(w2b + (size_t)(s * 64 + lane) * 8);
    f32x4 a2 = {0, 0, 0, 0};
#pragma unroll
    for (int s = 0; s < 8; s++) {
      bf16x8 af = *(const bf16x8*)(hid_s + (w * 16 + lo) * 264 + s * 32 + hi * 8);
      a2 = MFMA16(af, wf2[s], a2);
    }
    float b2c = b2[lo];
#pragma unroll
    for (int r = 0; r < 4; r++) {
      int rowl = w * 16 + hi * 4 + r;
      float v = a2[r] + b2c;
      act[(size_t)(row0 + rowl) * 16 + lo] = v;
      float m = v;
      m = fmaxf(m, __shfl_xor(m, 1));
      m = fmaxf(m, __shfl_xor(m, 2));
      m = fmaxf(m, __shfl_xor(m, 4));
      m = fmaxf(m, __shfl_xor(m, 8));
      float se = expf(v - m);
      se += __shfl_xor(se, 1);
      se += __shfl_xor(se, 2);
      se += __shfl_xor(se, 4);
      se += __shfl_xor(se, 8);
      int lbl = u[row0 + rowl];
      float vl = __shfl(v, (lane & 48) + lbl);
      float ce = -(vl - m - logf(se));
      if (lo == 0) ces += ce;
    }
  }
  red[tid] = ces;
  __syncthreads();
  for (int st = 256; st > 0; st >>= 1) {
    if (tid < st) red[tid] += red[tid + st];
    __syncthreads();
  }
  if (tid == 0) l1p[blockIdx.x] = red[0];
}

// world model + MSE (MFMA, weight-stationary): 64 rows/block, 8 waves
__global__ __launch_bounds__(512) void k_wm(
    const float* __restrict__ obs, const float* __restrict__ act,
    const unsigned short* __restrict__ w1b, const unsigned short* __restrict__ w2b,
    const float* __restrict__ b1, const float* __restrict__ b2,
    const float* __restrict__ obsn,
    float* __restrict__ onh, float* __restrict__ l2p)
{
  __shared__ __align__(16) unsigned short in_s[64 * 264];
  __shared__ __align__(16) unsigned short act_bs[8 * 128];
  __shared__ float red[512];
  int tid = threadIdx.x, w = tid >> 6, lane = tid & 63;
  int lo = lane & 15, hi = lane >> 4;
  int row0 = blockIdx.x * 64, e0 = row0 >> 3;
  for (int i = tid; i < 1024; i += 512) act_bs[i] = f2bf(act[(size_t)e0 * 128 + i]);
  for (int i = tid; i < 8192; i += 512) {
    int r = i >> 7, c = i & 127;
    in_s[r * 264 + c] = f2bf(obs[(size_t)(row0 + r) * 128 + c]);
  }
  bf16x8 wf1[2][8], wf2[8];
#pragma unroll
  for (int cc = 0; cc < 2; cc++)
#pragma unroll
    for (int s = 0; s < 8; s++)
      wf1[cc][s] = *(const bf16x8*)(w1b + (size_t)(((2 * w + cc) * 8 + s) * 64 + lane) * 8);
#pragma unroll
  for (int s = 0; s < 8; s++)
    wf2[s] = *(const bf16x8*)(w2b + (size_t)((w * 8 + s) * 64 + lane) * 8);
  __syncthreads();
  for (int i = tid; i < 8192; i += 512) {
    int r = i >> 7, c = i & 127;
    in_s[r * 264 + 128 + c] = ((c >> 4) == (r & 7)) ? (unsigned short)0 : act_bs[(r >> 3) * 128 + c];
  }
  __syncthreads();
  f32x4 acc[4][2];
#pragma unroll
  for (int rt = 0; rt < 4; rt++) { acc[rt][0] = {0,0,0,0}; acc[rt][1] = {0,0,0,0}; }
#pragma unroll
  for (int s = 0; s < 8; s++)
#pragma unroll
    for (int rt = 0; rt < 4; rt++) {
      bf16x8 af = *(const bf16x8*)(in_s + (rt * 16 + lo) * 264 + s * 32 + hi * 8);
      acc[rt][0] = MFMA16(af, wf1[0][s], acc[rt][0]);
      acc[rt][1] = MFMA16(af, wf1[1][s], acc[rt][1]);
    }
  float b1a = b1[32 * w + lo], b1b = b1[32 * w + 16 + lo];
  __syncthreads();
#pragma unroll
  for (int rt = 0; rt < 4; rt++)
#pragma unroll
    for (int r = 0; r < 4; r++) {
      int rowl = rt * 16 + hi * 4 + r;
      in_s[rowl * 264 + 32 * w + lo]      = f2bf(fmaxf(acc[rt][0][r] + b1a, 0.f));
      in_s[rowl * 264 + 32 * w + 16 + lo] = f2bf(fmaxf(acc[rt][1][r] + b1b, 0.f));
    }
  __syncthreads();
  f32x4 acc2[4];
#pragma unroll
  for (int rt = 0; rt < 4; rt++) acc2[rt] = {0, 0, 0, 0};
#pragma unroll
  for (int s = 0; s < 8; s++)
#pragma unroll
    for (int rt = 0; rt < 4; rt++) {
      bf16x8 af = *(const bf16x8*)(in_s + (rt * 16 + lo) * 264 + s * 32 + hi * 8);
      acc2[rt] = MFMA16(af, wf2[s], acc2[rt]);
    }
  int col = 16 * w + lo;
  float b2c = b2[col];
  float ms = 0.f;
#pragma unroll
  for (int rt = 0; rt < 4; rt++)
#pragma unroll
    for (int r = 0; r < 4; r++) {
      int row = row0 + rt * 16 + hi * 4 + r;
      float v = acc2[rt][r] + b2c;
      onh[(size_t)row * 128 + col] = v;
      float d = v - obsn[(size_t)row * 128 + col];
      ms = fmaf(d, d, ms);
    }
  red[tid] = ms;
  __syncthreads();
  for (int st = 256; st > 0; st >>= 1) {
    if (tid < st) red[tid] += red[tid + st];
    __syncthreads();
  }
  if (tid == 0) l2p[blockIdx.x] = red[0];
}

// query (MFMA, weight-stationary): 64 rows/block, 8 waves (c = w&3, row-half = w>>2)
__global__ __launch_bounds__(512) void k_query(
    const float* __restrict__ obs, const float* __restrict__ onh,
    const unsigned short* __restrict__ wqb, const float* __restrict__ bq,
    float* __restrict__ qry)
{
  __shared__ __align__(16) unsigned short in_s[64 * 264];
  int tid = threadIdx.x, w = tid >> 6, lane = tid & 63;
  int lo = lane & 15, hi = lane >> 4;
  int row0 = blockIdx.x * 64;
  for (int i = tid; i < 8192; i += 512) {
    int r = i >> 7, c = i & 127;
    in_s[r * 264 + c]       = f2bf(obs[(size_t)(row0 + r) * 128 + c]);
    in_s[r * 264 + 128 + c] = f2bf(onh[(size_t)(row0 + r) * 128 + c]);
  }
  int c = w & 3, rth = w >> 2;
  bf16x8 wf[8];
#pragma unroll
  for (int s = 0; s < 8; s++)
    wf[s] = *(const bf16x8*)(wqb + (size_t)((c * 8 + s) * 64 + lane) * 8);
  __syncthreads();
  f32x4 acc[2];
  acc[0] = {0, 0, 0, 0}; acc[1] = {0, 0, 0, 0};
#pragma unroll
  for (int s = 0; s < 8; s++)
#pragma unroll
    for (int rl = 0; rl < 2; rl++) {
      bf16x8 af = *(const bf16x8*)(in_s + ((rth * 2 + rl) * 16 + lo) * 264 + s * 32 + hi * 8);
      acc[rl] = MFMA16(af, wf[s], acc[rl]);
    }
  float bqc = bq[16 * c + lo];
#pragma unroll
  for (int rl = 0; rl < 2; rl++)
#pragma unroll
    for (int r = 0; r < 4; r++) {
      int row = row0 + (rth * 2 + rl) * 16 + hi * 4 + r;
      qry[(size_t)row * 64 + 16 * c + lo] = acc[rl][r] + bqc;
    }
}

// fused key + value + attention: 32 rows/block (4 episodes), wave = episode
__global__ __launch_bounds__(256) void k_kva(
    const float* __restrict__ h, const float* __restrict__ act,
    const float* __restrict__ ws, const float* __restrict__ bk,
    const float* __restrict__ bv1, const float* __restrict__ bv2,
    const float* __restrict__ qry, float* __restrict__ qout)
{
  __shared__ __align__(16) float in_s[32 * 80];
  __shared__ __align__(16) float hid_s[32 * 64];
  __shared__ __align__(16) float key_s[32 * 68];
  __shared__ float val_s[32 * 16];
  __shared__ float qs[4][64];
  int tid = threadIdx.x, w = tid >> 6, lane = tid & 63;
  int row0 = blockIdx.x * 32;
  for (int i = tid; i < 2048; i += 256) {
    int r = i >> 6, c = i & 63;
    in_s[r * 80 + c] = h[(size_t)row0 * 64 + i];
  }
  for (int i = tid; i < 512; i += 256) {
    int r = i >> 4, c = i & 15;
    in_s[r * 80 + 64 + c] = act[(size_t)row0 * 16 + i];
  }
  __syncthreads();
  const float* w1T = ws + T_WV1;
  const float* w2T = ws + T_WV2;
  const float* wkT = ws + T_WK;
  // value layer1: hid = relu([h|act] @ wv1T + bv1)
  float acc[8];
#pragma unroll
  for (int r = 0; r < 8; r++) acc[r] = bv1[lane];
  for (int k = 0; k < 80; k += 4) {
    float b[4];
#pragma unroll
    for (int j = 0; j < 4; j++) b[j] = w1T[(k + j) * 64 + lane];
#pragma unroll
    for (int r = 0; r < 8; r++) {
      float4 a = LD4(in_s + (w * 8 + r) * 80 + k);
      acc[r] = fmaf(a.x, b[0], fmaf(a.y, b[1], fmaf(a.z, b[2], fmaf(a.w, b[3], acc[r]))));
    }
  }
#pragma unroll
  for (int r = 0; r < 8; r++) hid_s[(w * 8 + r) * 64 + lane] = fmaxf(acc[r], 0.f);
  // key: act @ wkT + bk  -> key_s (stride 68)
  float ka[8];
#pragma unroll
  for (int r = 0; r < 8; r++) ka[r] = bk[lane];
  for (int k = 0; k < 16; k += 4) {
    float b[4];
#pragma unroll
    for (int j = 0; j < 4; j++) b[j] = wkT[(k + j) * 64 + lane];
#pragma unroll
    for (int r = 0; r < 8; r++) {
      float4 a = LD4(in_s + (w * 8 + r) * 80 + 64 + k);
      ka[r] = fmaf(a.x, b[0], fmaf(a.y, b[1], fmaf(a.z, b[2], fmaf(a.w, b[3], ka[r]))));
    }
  }
#pragma unroll
  for (int r = 0; r < 8; r++) key_s[(w * 8 + r) * 68 + lane] = ka[r];
  // value layer2 (wave-local hid rows)
  int col = lane & 15, kq = lane >> 4;
  float a2[8] = {0, 0, 0, 0, 0, 0, 0, 0};
  for (int kk = 0; kk < 16; kk += 4) {
    int k = kq * 16 + kk;
    float b[4];
#pragma unroll
    for (int j = 0; j < 4; j++) b[j] = w2T[(k + j) * 16 + col];
#pragma unroll
    for (int r = 0; r < 8; r++) {
      float4 a = LD4(hid_s + (w * 8 + r) * 64 + k);
      a2[r] = fmaf(a.x, b[0], fmaf(a.y, b[1], fmaf(a.z, b[2], fmaf(a.w, b[3], a2[r]))));
    }
  }
#pragma unroll
  for (int r = 0; r < 8; r++) {
    a2[r] += __shfl_xor(a2[r], 16);
    a2[r] += __shfl_xor(a2[r], 32);
  }
  if (lane < 16) {
#pragma unroll
    for (int r = 0; r < 8; r++) val_s[(w * 8 + r) * 16 + col] = a2[r] + bv2[col];
  }
  // attention: wave w = episode (rows w*8 .. w*8+7, all written by this wave)
  int j = lane >> 3, p = lane & 7;
  for (int rr = 0; rr < 8; rr++) {
    int b = row0 + w * 8 + rr;
    qs[w][lane] = qry[(size_t)b * 64 + lane];
    const float* krow = key_s + (w * 8 + j) * 68;
    float s = 0.f;
#pragma unroll
    for (int t = 0; t < 8; t++) {
      int d = p * 8 + t;
      s = fmaf(qs[w][d], krow[d], s);
    }
    s += __shfl_xor(s, 1);
    s += __shfl_xor(s, 2);
    s += __shfl_xor(s, 4);
    float score = (j == rr) ? -1e9f : s * 0.125f;
    float sc[8];
    float m = -1e30f;
#pragma unroll
    for (int jj = 0; jj < 8; jj++) {
      sc[jj] = __shfl(score, jj * 8);
      m = fmaxf(m, sc[jj]);
    }
    float ssum = 0.f;
#pragma unroll
    for (int jj = 0; jj < 8; jj++) { sc[jj] = expf(sc[jj] - m); ssum += sc[jj]; }
    float inv = 1.f / ssum;
    int c = lane & 15, g = lane >> 4;
    const float* vb = val_s + w * 8 * 16;
    float outv = sc[g] * inv * vb[g * 16 + c] + sc[g + 4] * inv * vb[(g + 4) * 16 + c];
    outv += __shfl_xor(outv, 16);
    outv += __shfl_xor(outv, 32);
    if (lane < 16) qout[(size_t)b * 16 + lane] = outv;
  }
}

__global__ __launch_bounds__(256) void k_losses(
    const float* __restrict__ l1p, const float* __restrict__ l2p, float* __restrict__ dout)
{
  __shared__ float red[256];
  int tid = threadIdx.x;
  float s1 = l1p[tid];
  float s2 = l2p[tid];
  red[tid] = s1;
  __syncthreads();
  for (int s = 128; s > 0; s >>= 1) {
    if (tid < s) red[tid] += red[tid + s];
    __syncthreads();
  }
  float S1 = red[0];
  __syncthreads();
  red[tid] = s2;
  __syncthreads();
  for (int s = 128; s > 0; s >>= 1) {
    if (tid < s) red[tid] += red[tid + s];
    __syncthreads();
  }
  if (tid == 0) {
    dout[DO_L1] = S1 * 7.f / 131072.f;
    dout[DO_L2] = red[0] / 2097152.f;
  }
}

extern "C" void kernel_launch(void* const* d_in, const int* in_sizes, int n_in,
                              void* d_out, int out_size, void* d_ws, size_t ws_size,
                              hipStream_t stream) {
  const float* inputs   = (const float*)d_in[0];
  const float* hidden   = (const float*)d_in[1];
  const float* obs      = (const float*)d_in[2];
  const float* obs_next = (const float*)d_in[3];
  const int*   u        = (const int*)d_in[4];
  const float* fc1_w = (const float*)d_in[5];   const float* fc1_b = (const float*)d_in[6];
  const float* wih   = (const float*)d_in[7];   const float* bih   = (const float*)d_in[8];
  const float* whh   = (const float*)d_in[9];   const float* bhh   = (const float*)d_in[10];
  const float* tm_w1 = (const float*)d_in[11];  const float* tm_b1 = (const float*)d_in[12];
  const float* tm_w2 = (const float*)d_in[13];  const float* tm_b2 = (const float*)d_in[14];
  const float* wm_w1 = (const float*)d_in[15];  const float* wm_b1 = (const float*)d_in[16];
  const float* wm_w2 = (const float*)d_in[17];  const float* wm_b2 = (const float*)d_in[18];
  const float* wq_w  = (const float*)d_in[19];  const float* wq_b  = (const float*)d_in[20];
  const float* wk_w  = (const float*)d_in[21];  const float* wk_b  = (const float*)d_in[22];
  const float* wv1_w = (const float*)d_in[23];  const float* wv1_b = (const float*)d_in[24];
  const float* wv2_w = (const float*)d_in[25];  const float* wv2_b = (const float*)d_in[26];

  float* ws   = (float*)d_ws;
  unsigned short* wsu = (unsigned short*)d_ws;
  float* out  = (float*)d_out;
  float* hbuf = out + DO_H;

  PrepP p;
  const float* tsr[6] = {fc1_w, wih, whh, wk_w, wv1_w, wv2_w};
  int tO[6]  = {64, 192, 192, 64, 64, 16};
  int tK[6]  = {152, 64, 64, 16, 80, 64};
  int tOf[6] = {T_FC1, T_WIH, T_WHH, T_WK, T_WV1, T_WV2};
  for (int i = 0; i < 6; i++) { p.tsrc[i] = tsr[i]; p.tO[i] = tO[i]; p.tK[i] = tK[i]; p.tOff[i] = tOf[i]; }
  const float* ssr[5] = {wm_w1, wm_w2, wq_w, tm_w1, tm_w2};
  int sO[5]  = {256, 128, 64, 256, 16};
  int sK[5]  = {256, 256, 256, 64, 256};
  int sSt[5] = {256, 256, 256, 72, 256};
  int sOf[5] = {B_WM1 * 2, B_WM2 * 2, B_WQ * 2, B_TM1 * 2, B_TM2 * 2};
  for (int i = 0; i < 5; i++) { p.ssrc[i] = ssr[i]; p.sO[i] = sO[i]; p.sK[i] = sK[i]; p.sSt[i] = sSt[i]; p.sOff[i] = sOf[i]; }
  p.tm_w1 = tm_w1; p.tm_b1 = tm_b1;

  k_prep<<<376, 256, 0, stream>>>(p, ws, wsu);
  k_trunk<<<ROWS / 32, 256, 0, stream>>>(inputs, hidden, ws, fc1_b, bih, bhh, hbuf);
  k_tm<<<ROWS / 64, 512, 0, stream>>>(hbuf, wsu + B_TM1 * 2, wsu + B_TM2 * 2, ws + TMB, tm_b2, u, ws + O_ACT, ws + O_L1P);
  k_wm<<<ROWS / 64, 512, 0, stream>>>(obs, ws + O_ACT, wsu + B_WM1 * 2, wsu + B_WM2 * 2, wm_b1, wm_b2, obs_next, ws + O_ONH, ws + O_L2P);
  k_query<<<ROWS / 64, 512, 0, stream>>>(obs, ws + O_ONH, wsu + B_WQ * 2, wq_b, ws + O_QRY);
  k_kva<<<ROWS / 32, 256, 0, stream>>>(hbuf, ws + O_ACT, ws, wk_b, wv1_b, wv2_b, ws + O_QRY, out);
  k_losses<<<1, 256, 0, stream>>>(ws + O_L1P, ws + O_L2P, out);
}